// Round 1
// baseline (3707.070 us; speedup 1.0000x reference)
//
#include <hip/hip_runtime.h>
#include <hip/hip_cooperative_groups.h>

typedef _Float16 f16;
typedef __attribute__((ext_vector_type(8))) _Float16 f16x8;
typedef __attribute__((ext_vector_type(4))) float f32x4;

namespace cg = cooperative_groups;

// ---------------------------------------------------------------- helpers
__device__ __forceinline__ float fast_sig(float x) { return 1.f / (1.f + __expf(-x)); }
// tanh via 1 - 2/(e^{2x}+1): saturates cleanly to +/-1, no NaN at extremes
__device__ __forceinline__ float fast_tanh(float x) {
  float e = __expf(2.f * x);
  return 1.f - 2.f / (e + 1.f);
}

// ---------------------------------------------------------------- f32 -> f16 convert
__global__ __launch_bounds__(256) void f2h_kernel(const float* __restrict__ src,
                                                  f16* __restrict__ dst) {
  size_t i = ((size_t)blockIdx.x * 256 + threadIdx.x) * 4;
  float4 v = *(const float4*)(src + i);
  dst[i + 0] = (f16)v.x;
  dst[i + 1] = (f16)v.y;
  dst[i + 2] = (f16)v.z;
  dst[i + 3] = (f16)v.w;
}

// gather embedding rows: xg[m,:] = (f16)emb[ids[m],:]   (one block per m, H=1024)
__global__ __launch_bounds__(256) void gather_rows(const float* __restrict__ emb,
                                                   const int* __restrict__ ids,
                                                   f16* __restrict__ xg) {
  int m = blockIdx.x;
  int i = threadIdx.x * 4;
  const float* src = emb + (size_t)ids[m] * 1024 + i;
  float4 v = *(const float4*)src;
  f16* d = xg + (size_t)m * 1024 + i;
  d[0] = (f16)v.x; d[1] = (f16)v.y; d[2] = (f16)v.z; d[3] = (f16)v.w;
}

// ---------------------------------------------------------------- h-state init (f16 slots)
__global__ __launch_bounds__(256) void init_h(const float* __restrict__ h0,
                                              f16* __restrict__ h1slot0,
                                              f16* __restrict__ h2slot0) {
  int i = blockIdx.x * 256 + threadIdx.x;  // grid 256 -> 65536
  h1slot0[i] = (f16)h0[i];
  h2slot0[i] = (f16)h0[65536 + i];
}

// ---------------------------------------------------------------- persistent 2-layer LSTM
// One cooperative launch runs all 64 timesteps. 256 blocks x 512 threads (8 waves),
// block p owns hidden units [4p,4p+4) of BOTH layers: 16 gate-rows x 4 matrices
// (Wih1,Whh1,Wih2,Whh2) = 128 KB f16 staged into LDS ONCE (converted from f32 here,
// so no f2h pass and no separate x@Wih1 pre-GEMM).
// Software pipeline: phase t computes layer1_t and layer2_{t-1} (both read only
// phase t-1 outputs) -> exactly one grid.sync() per phase, 64 syncs total.
// LDS weight layout is MFMA-B-fragment-linear: slot(ks,lane) = W[n=lane&15][k=ks*32+(lane>>4)*8..+8]
// -> ds_read_b128 at stride-1 across the wave, conflict-free.
// Cell state: one f32 register per thread (tid<256: layer1, tid>=256: layer2).
__global__ __launch_bounds__(512, 1) void lstm_persistent(
    const float* __restrict__ w_ih, const float* __restrict__ w_hh,  // [2][4096][1024] f32
    const float* __restrict__ b_ih, const float* __restrict__ b_hh,  // [2][4096] f32
    const float* __restrict__ c0,                                    // [2][64][1024] f32
    const f16* __restrict__ xg,                                      // [4096][1024] f16
    f16* __restrict__ h1buf,                                         // 2 ping-pong slots
    f16* __restrict__ h2hist,                                        // 65 slots (slot0 = init)
    float* __restrict__ hf, float* __restrict__ cf) {                // [2][64][1024] f32
  __shared__ f16 wlds[65536];               // 4 matrices x 2048 slots x 8 f16 = 128 KB
  __shared__ float red1[2048], red2[2048];  // [wave][16m][16n] partials, 8 KB each
  __shared__ float bsum[32];                // b_ih+b_hh for this block's 16 rows x 2 layers
  const int p = blockIdx.x;
  const int tid = threadIdx.x;
  const int lane = tid & 63, w = tid >> 6;
  const int mt = w & 3, kh = w >> 2;        // wave = (batch-tile, K-half)
  const int am = mt * 16 + (lane & 15);     // A-fragment batch row
  const int kq = (lane >> 4) * 8;

  // ---- one-time staging: 8192 slots / 512 threads = 16 each
  for (int s = tid; s < 8192; s += 512) {
    const int mat = s >> 11, sl = s & 2047;       // mat: 0=Wih1 1=Whh1 2=Wih2 3=Whh2
    const int ln = sl & 63, ks = sl >> 6;
    const int n = ln & 15;                        // n = gate*4 + unit_local
    const int row = (n >> 2) * 1024 + p * 4 + (n & 3) + ((mat >= 2) ? 4096 : 0);
    const int k = ks * 32 + (ln >> 4) * 8;
    const float* src = ((mat & 1) ? w_hh : w_ih) + (size_t)row * 1024 + k;
    float4 v0 = *(const float4*)src;
    float4 v1 = *(const float4*)(src + 4);
    f16x8 hv = {(f16)v0.x, (f16)v0.y, (f16)v0.z, (f16)v0.w,
                (f16)v1.x, (f16)v1.y, (f16)v1.z, (f16)v1.w};
    *(f16x8*)(wlds + (size_t)mat * 16384 + (size_t)sl * 8) = hv;
  }
  if (tid < 32) {
    int l = tid >> 4, n = tid & 15;
    int row = l * 4096 + (n >> 2) * 1024 + p * 4 + (n & 3);
    bsum[tid] = b_ih[row] + b_hh[row];
  }
  float creg;
  {
    int q = tid & 255;
    size_t idx = (size_t)(q >> 2) * 1024 + p * 4 + (q & 3);
    creg = (tid < 256) ? c0[idx] : c0[65536 + idx];
  }
  __syncthreads();

  cg::grid_group grid = cg::this_grid();

  for (int t = 0; t <= 64; ++t) {
    const f16* h1p = h1buf + (size_t)(t & 1) * 65536;  // h1_{t-1}

    if (t < 64) {  // ---- layer-1 gates for timestep t: xg[t]@Wih1^T + h1p@Whh1^T
      f32x4 acc = {0.f, 0.f, 0.f, 0.f};
      const f16* xrow = xg + ((size_t)t * 64 + am) * 1024;
      const f16* hrow = h1p + (size_t)am * 1024;
#pragma unroll 4
      for (int ks = kh * 16; ks < kh * 16 + 16; ++ks) {
        int k = ks * 32 + kq;
        f16x8 b0 = *(const f16x8*)(wlds + (size_t)ks * 512 + lane * 8);
        f16x8 a0 = *(const f16x8*)(xrow + k);
        acc = __builtin_amdgcn_mfma_f32_16x16x32_f16(a0, b0, acc, 0, 0, 0);
        f16x8 b1 = *(const f16x8*)(wlds + 16384 + (size_t)ks * 512 + lane * 8);
        f16x8 a1 = *(const f16x8*)(hrow + k);
        acc = __builtin_amdgcn_mfma_f32_16x16x32_f16(a1, b1, acc, 0, 0, 0);
      }
#pragma unroll
      for (int q = 0; q < 4; q++)
        red1[w * 256 + ((lane >> 4) * 4 + q) * 16 + (lane & 15)] = acc[q];
    }

    if (t > 0) {  // ---- layer-2 gates for timestep t-1: h1_{t-1}@Wih2^T + h2_{t-2}@Whh2^T
      f32x4 acc = {0.f, 0.f, 0.f, 0.f};
      const f16* hrow = h1p + (size_t)am * 1024;
      const f16* h2row = h2hist + ((size_t)(t - 1) * 64 + am) * 1024;
#pragma unroll 4
      for (int ks = kh * 16; ks < kh * 16 + 16; ++ks) {
        int k = ks * 32 + kq;
        f16x8 b0 = *(const f16x8*)(wlds + 32768 + (size_t)ks * 512 + lane * 8);
        f16x8 a0 = *(const f16x8*)(hrow + k);
        acc = __builtin_amdgcn_mfma_f32_16x16x32_f16(a0, b0, acc, 0, 0, 0);
        f16x8 b1 = *(const f16x8*)(wlds + 49152 + (size_t)ks * 512 + lane * 8);
        f16x8 a1 = *(const f16x8*)(h2row + k);
        acc = __builtin_amdgcn_mfma_f32_16x16x32_f16(a1, b1, acc, 0, 0, 0);
      }
#pragma unroll
      for (int q = 0; q < 4; q++)
        red2[w * 256 + ((lane >> 4) * 4 + q) * 16 + (lane & 15)] = acc[q];
    }
    __syncthreads();

    // ---- elementwise: threads 0-255 -> layer1, 256-511 -> layer2
    if (t < 64 && tid < 256) {
      const int b = tid >> 2, ul = tid & 3;
      const int mrow = (b & 15) * 16, mtb = (b >> 4) * 256;
      float g4[4];
#pragma unroll
      for (int g = 0; g < 4; g++) {
        int n = g * 4 + ul;
        g4[g] = red1[mtb + mrow + n] + red1[1024 + mtb + mrow + n] + bsum[n];
      }
      float cn = fast_sig(g4[1]) * creg + fast_sig(g4[0]) * fast_tanh(g4[2]);
      float hn = fast_sig(g4[3]) * fast_tanh(cn);
      creg = cn;
      const int u = p * 4 + ul;
      h1buf[(size_t)((t & 1) ^ 1) * 65536 + (size_t)b * 1024 + u] = (f16)hn;
      if (t == 63) {
        hf[(size_t)b * 1024 + u] = hn;
        cf[(size_t)b * 1024 + u] = cn;
      }
    }
    if (t > 0 && tid >= 256) {
      const int q = tid & 255;
      const int b = q >> 2, ul = q & 3;
      const int mrow = (b & 15) * 16, mtb = (b >> 4) * 256;
      float g4[4];
#pragma unroll
      for (int g = 0; g < 4; g++) {
        int n = g * 4 + ul;
        g4[g] = red2[mtb + mrow + n] + red2[1024 + mtb + mrow + n] + bsum[16 + n];
      }
      float cn = fast_sig(g4[1]) * creg + fast_sig(g4[0]) * fast_tanh(g4[2]);
      float hn = fast_sig(g4[3]) * fast_tanh(cn);
      creg = cn;
      const int u = p * 4 + ul;
      h2hist[(size_t)t * 65536 + (size_t)b * 1024 + u] = (f16)hn;
      if (t == 64) {
        hf[65536 + (size_t)b * 1024 + u] = hn;
        cf[65536 + (size_t)b * 1024 + u] = cn;
      }
    }
    if (t < 64) grid.sync();  // uniform guard; no sync needed after final phase
  }
}

// ---------------------------------------------------------------- simple direct-global GEMM
// C[m,n] = sum_k A[m,k]*B[n,k] (+bias1+bias2)(tanh). A = A1 rows [*,K1] then A2 for k>=K1.
// B row-major [N, Ktot], all f16. Block = 64x64 tile, 4 waves; wave w owns 16 m-rows.
template <typename OutT>
__global__ __launch_bounds__(256) void gemm_simple(
    const f16* __restrict__ A1, const f16* __restrict__ A2,
    const f16* __restrict__ Bm,
    const float* __restrict__ bias1, const float* __restrict__ bias2,
    OutT* __restrict__ C, int ldc,
    int K1, int Ktot, int do_tanh) {
  const int tid = threadIdx.x;
  const int lane = tid & 63;
  const int w = tid >> 6;
  const int m0 = blockIdx.y * 64 + w * 16;  // this wave's 16 m-rows
  const int n0 = blockIdx.x * 64;
  const int am = m0 + (lane & 15);
  const int kq = (lane >> 4) * 8;           // quad's k-offset within a 32-chunk
  const int K2 = Ktot - K1;

  f32x4 acc[4];
#pragma unroll
  for (int j = 0; j < 4; j++) acc[j] = (f32x4){0.f, 0.f, 0.f, 0.f};

  for (int k0 = 0; k0 < Ktot; k0 += 32) {
    int k = k0 + kq;
    f16x8 av;
    if (k < K1)
      av = *(const f16x8*)(A1 + (size_t)am * K1 + k);
    else
      av = *(const f16x8*)(A2 + (size_t)am * K2 + (k - K1));
#pragma unroll
    for (int j = 0; j < 4; j++) {
      f16x8 bv = *(const f16x8*)(Bm + (size_t)(n0 + j * 16 + (lane & 15)) * Ktot + k);
      acc[j] = __builtin_amdgcn_mfma_f32_16x16x32_f16(av, bv, acc[j], 0, 0, 0);
    }
  }

  const int r0 = (lane >> 4) * 4;
  const int cc = lane & 15;
#pragma unroll
  for (int j = 0; j < 4; j++) {
    int col = n0 + j * 16 + cc;
    float bv = 0.f;
    if (bias1) bv += bias1[col];
    if (bias2) bv += bias2[col];
#pragma unroll
    for (int q = 0; q < 4; q++) {
      float v = acc[j][q] + bv;
      if (do_tanh) v = fast_tanh(v);
      C[(size_t)(m0 + r0 + q) * ldc + col] = (OutT)v;
    }
  }
}

// ---------------------------------------------------------------- attention scores/softmax/wc
// one block per (t,b): scores[s] = ctx[s,b,:].q ; softmax ; wc = a @ ctx[:,b,:]
__global__ __launch_bounds__(256) void attn_kernel(
    const float* __restrict__ Q,   // [4096][1024] f32
    const float* __restrict__ ctx, // context f32 [S=64][B=64][H=1024]
    f16* __restrict__ wc,          // [4096][1024] f16
    float* __restrict__ attn_out) {// [64][64] (t==63 only)
  const int m = blockIdx.x;
  const int b = m & 63;
  const int t = m >> 6;
  const int tid = threadIdx.x;
  const int lane = tid & 63;
  const int w = tid >> 6;
  __shared__ float s_sc[64];
  __shared__ float s_at[64];

  const float* qp = Q + (size_t)m * 1024 + lane * 16;
  float qf[16];
#pragma unroll
  for (int i = 0; i < 4; i++) {
    float4 v = *(const float4*)(qp + i * 4);
    qf[i * 4 + 0] = v.x; qf[i * 4 + 1] = v.y; qf[i * 4 + 2] = v.z; qf[i * 4 + 3] = v.w;
  }

  // scores: wave w handles s in [w*16, w*16+16)
  for (int si = 0; si < 16; si++) {
    int s = w * 16 + si;
    const float* cp = ctx + ((size_t)s * 64 + b) * 1024 + lane * 16;
    float d = 0.f;
#pragma unroll
    for (int i = 0; i < 4; i++) {
      float4 v = *(const float4*)(cp + i * 4);
      d += v.x * qf[i * 4] + v.y * qf[i * 4 + 1] + v.z * qf[i * 4 + 2] + v.w * qf[i * 4 + 3];
    }
#pragma unroll
    for (int off = 32; off > 0; off >>= 1) d += __shfl_down(d, off, 64);
    if (lane == 0) s_sc[s] = d;
  }
  __syncthreads();
  if (w == 0) {
    float v = s_sc[lane];
    float mx = v;
#pragma unroll
    for (int off = 32; off > 0; off >>= 1) mx = fmaxf(mx, __shfl_xor(mx, off, 64));
    float e = __expf(v - mx);
    float sm = e;
#pragma unroll
    for (int off = 32; off > 0; off >>= 1) sm += __shfl_xor(sm, off, 64);
    float a = e / sm;
    s_at[lane] = a;
    if (t == 63) attn_out[b * 64 + lane] = a;
  }
  __syncthreads();
#pragma unroll
  for (int rep = 0; rep < 4; rep++) {
    int h = rep * 256 + tid;
    float acc = 0.f;
    for (int s = 0; s < 64; s++)
      acc += s_at[s] * ctx[((size_t)s * 64 + b) * 1024 + h];
    wc[(size_t)m * 1024 + h] = (f16)acc;
  }
}

// ---------------------------------------------------------------- launch
extern "C" void kernel_launch(void* const* d_in, const int* in_sizes, int n_in,
                              void* d_out, int out_size, void* d_ws, size_t ws_size,
                              hipStream_t stream) {
  const int*   input = (const int*)d_in[0];
  const float* h0    = (const float*)d_in[1];
  const float* c0    = (const float*)d_in[2];
  const float* ctx   = (const float*)d_in[3];
  const float* emb   = (const float*)d_in[4];
  const float* w_ih  = (const float*)d_in[5];
  const float* w_hh  = (const float*)d_in[6];
  const float* b_ih  = (const float*)d_in[7];
  const float* b_hh  = (const float*)d_in[8];
  const float* w_in  = (const float*)d_in[9];
  const float* w_out = (const float*)d_in[10];
  float* out = (float*)d_out;

  char* ws = (char*)d_ws;
  size_t off = 0;
  auto alloc = [&](size_t bytes) {
    char* p = ws + off;
    off += (bytes + 255) & ~(size_t)255;
    return p;
  };
  f16*   h2hist = (f16*)alloc((size_t)65 * 65536 * 2);     // slot0=init, slot t+1=h2_t
  f16*   h1buf  = (f16*)alloc((size_t)2 * 65536 * 2);      // layer-1 h ping-pong
  float* Q      = (float*)alloc((size_t)4096 * 1024 * 4);  // f32 for attention accuracy
  f16*   wc     = (f16*)alloc((size_t)4096 * 1024 * 2);
  f16*   xg     = (f16*)alloc((size_t)4096 * 1024 * 2);    // gathered emb rows
  f16*   winh   = (f16*)alloc((size_t)1024 * 1024 * 2);
  f16*   wouth  = (f16*)alloc((size_t)1024 * 2048 * 2);

  float* outs = out;                              // [T*B][1024]
  float* hf   = out + (size_t)4096 * 1024;        // [2][64][1024]
  float* cf   = hf + 131072;
  float* attn = cf + 131072;                      // [64][64]

  // ---- small weight converts (only the ones still needed by K3/K5) + emb gather
  f2h_kernel<<<1024, 256, 0, stream>>>(w_in, winh);   // 1024*1024
  f2h_kernel<<<2048, 256, 0, stream>>>(w_out, wouth); // 1024*2048
  gather_rows<<<4096, 256, 0, stream>>>(emb, input, xg);
  init_h<<<256, 256, 0, stream>>>(h0, h1buf, h2hist);

  // ---- K2: entire 64-step 2-layer LSTM in ONE cooperative kernel.
  // Weights live in LDS (128 KB/block incl. Wih1 -> no X1 pre-GEMM, no w_ih/w_hh f2h).
  {
    void* args[] = {(void*)&w_ih, (void*)&w_hh, (void*)&b_ih, (void*)&b_hh,
                    (void*)&c0, (void*)&xg, (void*)&h1buf, (void*)&h2hist,
                    (void*)&hf, (void*)&cf};
    hipLaunchCooperativeKernel(lstm_persistent, dim3(256), dim3(512), args, 0, stream);
  }

  // K3: Q = H2_all @ w_in^T   [M=4096,N=1024,K=1024], f32 out
  gemm_simple<float><<<dim3(16, 64), 256, 0, stream>>>(h2hist + 65536, nullptr,
      winh, nullptr, nullptr, Q, 1024, 1024, 1024, 0);

  // K4: scores -> softmax -> weighted context (+ final-step attention output), all f32
  attn_kernel<<<4096, 256, 0, stream>>>(Q, ctx, wc, attn);

  // K5: outs = tanh([wc | H2_all] @ w_out^T)   [M=4096,N=1024,K=2048], f32 out
  gemm_simple<float><<<dim3(16, 64), 256, 0, stream>>>(wc, h2hist + 65536,
      wouth, nullptr, nullptr, outs, 1024, 1024, 2048, 1);
}

// Round 2
// 2140.274 us; speedup vs baseline: 1.7321x; 1.7321x over previous
//
#include <hip/hip_runtime.h>

typedef _Float16 f16;
typedef __attribute__((ext_vector_type(4))) _Float16 f16x4;
typedef __attribute__((ext_vector_type(8))) _Float16 f16x8;
typedef __attribute__((ext_vector_type(4))) float f32x4;

// ---------------------------------------------------------------- helpers
__device__ __forceinline__ float fast_sig(float x) { return 1.f / (1.f + __expf(-x)); }
// tanh via 1 - 2/(e^{2x}+1): saturates cleanly to +/-1, no NaN at extremes
__device__ __forceinline__ float fast_tanh(float x) {
  float e = __expf(2.f * x);
  return 1.f - 2.f / (e + 1.f);
}

// agent-scope (device-coherent, sc1) 16B load as two 8B relaxed atomic loads:
// bypasses the per-XCD L2 so cross-XCD h-vectors are read fresh from LLC
// without any cache-maintenance fence.
__device__ __forceinline__ f16x8 ld_dev(const f16* p) {
  unsigned long long u0 = __hip_atomic_load((const unsigned long long*)p,
                                            __ATOMIC_RELAXED, __HIP_MEMORY_SCOPE_AGENT);
  unsigned long long u1 = __hip_atomic_load((const unsigned long long*)p + 1,
                                            __ATOMIC_RELAXED, __HIP_MEMORY_SCOPE_AGENT);
  union { unsigned long long u; f16x4 h; } a, b;
  a.u = u0; b.u = u1;
  return __builtin_shufflevector(a.h, b.h, 0, 1, 2, 3, 4, 5, 6, 7);
}

// ---------------------------------------------------------------- f32 -> f16 convert
__global__ __launch_bounds__(256) void f2h_kernel(const float* __restrict__ src,
                                                  f16* __restrict__ dst) {
  size_t i = ((size_t)blockIdx.x * 256 + threadIdx.x) * 4;
  float4 v = *(const float4*)(src + i);
  dst[i + 0] = (f16)v.x;
  dst[i + 1] = (f16)v.y;
  dst[i + 2] = (f16)v.z;
  dst[i + 3] = (f16)v.w;
}

// gather embedding rows: xg[m,:] = (f16)emb[ids[m],:]   (one block per m, H=1024)
__global__ __launch_bounds__(256) void gather_rows(const float* __restrict__ emb,
                                                   const int* __restrict__ ids,
                                                   f16* __restrict__ xg) {
  int m = blockIdx.x;
  int i = threadIdx.x * 4;
  const float* src = emb + (size_t)ids[m] * 1024 + i;
  float4 v = *(const float4*)src;
  f16* d = xg + (size_t)m * 1024 + i;
  d[0] = (f16)v.x; d[1] = (f16)v.y; d[2] = (f16)v.z; d[3] = (f16)v.w;
}

// ---------------------------------------------------------------- h-state init + barrier reset
__global__ __launch_bounds__(256) void init_h(const float* __restrict__ h0,
                                              f16* __restrict__ h1slot0,
                                              f16* __restrict__ h2slot0,
                                              unsigned* __restrict__ bar) {
  int i = blockIdx.x * 256 + threadIdx.x;  // grid 256 -> 65536
  h1slot0[i] = (f16)h0[i];
  h2slot0[i] = (f16)h0[65536 + i];
  if (i == 0) *bar = 0;
}

// ---------------------------------------------------------------- persistent 2-layer LSTM
// One cooperative launch runs all 64 timesteps. 256 blocks x 512 threads (8 waves),
// block p owns hidden units [4p,4p+4) of BOTH layers: 16 gate-rows x 4 matrices
// (Wih1,Whh1,Wih2,Whh2) = 128 KB f16 staged into LDS ONCE.
// Software pipeline: phase t computes layer1_t and layer2_{t-1} in ONE merged
// K-loop (shared h1 operand loaded once).
// Cross-block sync: NOT cg::grid.sync() (measured ~50 us/phase on 8-XCD MI355X —
// device-scope fence forces L2 writeback/invalidate). Instead: all cross-phase
// data (h1buf, h2hist) moves via agent-scope (sc1) relaxed atomics which
// write through to / read from the LLC, so the barrier is just a vmcnt drain
// (implicit in __syncthreads) + one LLC atomicAdd per block + spin.
__global__ __launch_bounds__(512, 1) void lstm_persistent(
    const float* __restrict__ w_ih, const float* __restrict__ w_hh,  // [2][4096][1024] f32
    const float* __restrict__ b_ih, const float* __restrict__ b_hh,  // [2][4096] f32
    const float* __restrict__ c0,                                    // [2][64][1024] f32
    const f16* __restrict__ xg,                                      // [4096][1024] f16
    f16* __restrict__ h1buf,                                         // 2 ping-pong slots
    f16* __restrict__ h2hist,                                        // 65 slots (slot0 = init)
    float* __restrict__ hf, float* __restrict__ cf,                  // [2][64][1024] f32
    unsigned* __restrict__ bar) {
  __shared__ f16 wlds[65536];               // 4 matrices x 2048 slots x 8 f16 = 128 KB
  __shared__ float red1[2048], red2[2048];  // [wave][16m][16n] partials, 8 KB each
  __shared__ float bsum[32];                // b_ih+b_hh for this block's 16 rows x 2 layers
  const int p = blockIdx.x;
  const int tid = threadIdx.x;
  const int lane = tid & 63, w = tid >> 6;
  const int mt = w & 3, kh = w >> 2;        // wave = (batch-tile, K-half)
  const int am = mt * 16 + (lane & 15);     // A-fragment batch row
  const int kq = (lane >> 4) * 8;

  // ---- one-time staging: 8192 slots / 512 threads = 16 each
  for (int s = tid; s < 8192; s += 512) {
    const int mat = s >> 11, sl = s & 2047;       // mat: 0=Wih1 1=Whh1 2=Wih2 3=Whh2
    const int ln = sl & 63, ks = sl >> 6;
    const int n = ln & 15;                        // n = gate*4 + unit_local
    const int row = (n >> 2) * 1024 + p * 4 + (n & 3) + ((mat >= 2) ? 4096 : 0);
    const int k = ks * 32 + (ln >> 4) * 8;
    const float* src = ((mat & 1) ? w_hh : w_ih) + (size_t)row * 1024 + k;
    float4 v0 = *(const float4*)src;
    float4 v1 = *(const float4*)(src + 4);
    f16x8 hv = {(f16)v0.x, (f16)v0.y, (f16)v0.z, (f16)v0.w,
                (f16)v1.x, (f16)v1.y, (f16)v1.z, (f16)v1.w};
    *(f16x8*)(wlds + (size_t)mat * 16384 + (size_t)sl * 8) = hv;
  }
  if (tid < 32) {
    int l = tid >> 4, n = tid & 15;
    int row = l * 4096 + (n >> 2) * 1024 + p * 4 + (n & 3);
    bsum[tid] = b_ih[row] + b_hh[row];
  }
  float creg;
  {
    int q = tid & 255;
    size_t idx = (size_t)(q >> 2) * 1024 + p * 4 + (q & 3);
    creg = (tid < 256) ? c0[idx] : c0[65536 + idx];
  }
  __syncthreads();

  for (int t = 0; t <= 64; ++t) {
    const f16* h1p = h1buf + (size_t)(t & 1) * 65536;  // h1_{t-1}
    // clamped addresses so edge phases stay straight-line (MFMA predicated off)
    const int tx = (t < 64) ? t : 63;
    const int t2 = (t > 0) ? t - 1 : 0;
    const f16* xrow = xg + ((size_t)tx * 64 + am) * 1024;
    const f16* hrow = h1p + (size_t)am * 1024;
    const f16* h2row = h2hist + ((size_t)t2 * 64 + am) * 1024;

    f32x4 acc1 = {0.f, 0.f, 0.f, 0.f};
    f32x4 acc2 = {0.f, 0.f, 0.f, 0.f};
#pragma unroll 4
    for (int ks = kh * 16; ks < kh * 16 + 16; ++ks) {
      int k = ks * 32 + kq;
      f16x8 xv = *(const f16x8*)(xrow + k);   // xg: immutable, normal cached load
      f16x8 hv = ld_dev(hrow + k);            // cross-phase: agent-scope
      f16x8 h2v = ld_dev(h2row + k);          // cross-phase: agent-scope
      f16x8 b0 = *(const f16x8*)(wlds + (size_t)ks * 512 + lane * 8);
      f16x8 b1 = *(const f16x8*)(wlds + 16384 + (size_t)ks * 512 + lane * 8);
      f16x8 b2 = *(const f16x8*)(wlds + 32768 + (size_t)ks * 512 + lane * 8);
      f16x8 b3 = *(const f16x8*)(wlds + 49152 + (size_t)ks * 512 + lane * 8);
      if (t < 64) {  // layer-1 gates, timestep t
        acc1 = __builtin_amdgcn_mfma_f32_16x16x32_f16(xv, b0, acc1, 0, 0, 0);
        acc1 = __builtin_amdgcn_mfma_f32_16x16x32_f16(hv, b1, acc1, 0, 0, 0);
      }
      if (t > 0) {   // layer-2 gates, timestep t-1
        acc2 = __builtin_amdgcn_mfma_f32_16x16x32_f16(hv, b2, acc2, 0, 0, 0);
        acc2 = __builtin_amdgcn_mfma_f32_16x16x32_f16(h2v, b3, acc2, 0, 0, 0);
      }
    }
    if (t < 64) {
#pragma unroll
      for (int q = 0; q < 4; q++)
        red1[w * 256 + ((lane >> 4) * 4 + q) * 16 + (lane & 15)] = acc1[q];
    }
    if (t > 0) {
#pragma unroll
      for (int q = 0; q < 4; q++)
        red2[w * 256 + ((lane >> 4) * 4 + q) * 16 + (lane & 15)] = acc2[q];
    }
    __syncthreads();

    // ---- elementwise: threads 0-255 -> layer1, 256-511 -> layer2
    if (t < 64 && tid < 256) {
      const int b = tid >> 2, ul = tid & 3;
      const int mrow = (b & 15) * 16, mtb = (b >> 4) * 256;
      float g4[4];
#pragma unroll
      for (int g = 0; g < 4; g++) {
        int n = g * 4 + ul;
        g4[g] = red1[mtb + mrow + n] + red1[1024 + mtb + mrow + n] + bsum[n];
      }
      float cn = fast_sig(g4[1]) * creg + fast_sig(g4[0]) * fast_tanh(g4[2]);
      float hn = fast_sig(g4[3]) * fast_tanh(cn);
      creg = cn;
      const int u = p * 4 + ul;
      if (t == 63) {
        hf[(size_t)b * 1024 + u] = hn;
        cf[(size_t)b * 1024 + u] = cn;
      }
      // pack 4 units (ul=0..3, same wave) -> one 8B agent-scope store
      float h1v = __shfl_down(hn, 1, 64);
      float h2s = __shfl_down(hn, 2, 64);
      float h3v = __shfl_down(hn, 3, 64);
      if (ul == 0) {
        union { f16x4 h; unsigned long long u64; } pk;
        pk.h = (f16x4){(f16)hn, (f16)h1v, (f16)h2s, (f16)h3v};
        f16* dst = h1buf + (size_t)((t & 1) ^ 1) * 65536 + (size_t)b * 1024 + p * 4;
        __hip_atomic_store((unsigned long long*)dst, pk.u64,
                           __ATOMIC_RELAXED, __HIP_MEMORY_SCOPE_AGENT);
      }
    }
    if (t > 0 && tid >= 256) {
      const int q = tid & 255;
      const int b = q >> 2, ul = q & 3;
      const int mrow = (b & 15) * 16, mtb = (b >> 4) * 256;
      float g4[4];
#pragma unroll
      for (int g = 0; g < 4; g++) {
        int n = g * 4 + ul;
        g4[g] = red2[mtb + mrow + n] + red2[1024 + mtb + mrow + n] + bsum[16 + n];
      }
      float cn = fast_sig(g4[1]) * creg + fast_sig(g4[0]) * fast_tanh(g4[2]);
      float hn = fast_sig(g4[3]) * fast_tanh(cn);
      creg = cn;
      const int u = p * 4 + ul;
      if (t == 64) {
        hf[65536 + (size_t)b * 1024 + u] = hn;
        cf[65536 + (size_t)b * 1024 + u] = cn;
      }
      float h1v = __shfl_down(hn, 1, 64);
      float h2s = __shfl_down(hn, 2, 64);
      float h3v = __shfl_down(hn, 3, 64);
      if (ul == 0) {
        union { f16x4 h; unsigned long long u64; } pk;
        pk.h = (f16x4){(f16)hn, (f16)h1v, (f16)h2s, (f16)h3v};
        f16* dst = h2hist + (size_t)t * 65536 + (size_t)b * 1024 + p * 4;
        __hip_atomic_store((unsigned long long*)dst, pk.u64,
                           __ATOMIC_RELAXED, __HIP_MEMORY_SCOPE_AGENT);
      }
    }

    if (t < 64) {
      // lightweight grid barrier: __syncthreads drains each wave's vmcnt
      // (agent stores committed to LLC), then one LLC atomic per block.
      __syncthreads();
      if (tid == 0) {
        __hip_atomic_fetch_add(bar, 1u, __ATOMIC_RELAXED, __HIP_MEMORY_SCOPE_AGENT);
        const unsigned target = 256u * (unsigned)(t + 1);
        while (__hip_atomic_load(bar, __ATOMIC_RELAXED, __HIP_MEMORY_SCOPE_AGENT) < target)
          __builtin_amdgcn_s_sleep(1);
      }
      __syncthreads();
    }
  }
}

// ---------------------------------------------------------------- simple direct-global GEMM
// C[m,n] = sum_k A[m,k]*B[n,k] (+bias1+bias2)(tanh). A = A1 rows [*,K1] then A2 for k>=K1.
// B row-major [N, Ktot], all f16. Block = 64x64 tile, 4 waves; wave w owns 16 m-rows.
template <typename OutT>
__global__ __launch_bounds__(256) void gemm_simple(
    const f16* __restrict__ A1, const f16* __restrict__ A2,
    const f16* __restrict__ Bm,
    const float* __restrict__ bias1, const float* __restrict__ bias2,
    OutT* __restrict__ C, int ldc,
    int K1, int Ktot, int do_tanh) {
  const int tid = threadIdx.x;
  const int lane = tid & 63;
  const int w = tid >> 6;
  const int m0 = blockIdx.y * 64 + w * 16;  // this wave's 16 m-rows
  const int n0 = blockIdx.x * 64;
  const int am = m0 + (lane & 15);
  const int kq = (lane >> 4) * 8;           // quad's k-offset within a 32-chunk
  const int K2 = Ktot - K1;

  f32x4 acc[4];
#pragma unroll
  for (int j = 0; j < 4; j++) acc[j] = (f32x4){0.f, 0.f, 0.f, 0.f};

  for (int k0 = 0; k0 < Ktot; k0 += 32) {
    int k = k0 + kq;
    f16x8 av;
    if (k < K1)
      av = *(const f16x8*)(A1 + (size_t)am * K1 + k);
    else
      av = *(const f16x8*)(A2 + (size_t)am * K2 + (k - K1));
#pragma unroll
    for (int j = 0; j < 4; j++) {
      f16x8 bv = *(const f16x8*)(Bm + (size_t)(n0 + j * 16 + (lane & 15)) * Ktot + k);
      acc[j] = __builtin_amdgcn_mfma_f32_16x16x32_f16(av, bv, acc[j], 0, 0, 0);
    }
  }

  const int r0 = (lane >> 4) * 4;
  const int cc = lane & 15;
#pragma unroll
  for (int j = 0; j < 4; j++) {
    int col = n0 + j * 16 + cc;
    float bv = 0.f;
    if (bias1) bv += bias1[col];
    if (bias2) bv += bias2[col];
#pragma unroll
    for (int q = 0; q < 4; q++) {
      float v = acc[j][q] + bv;
      if (do_tanh) v = fast_tanh(v);
      C[(size_t)(m0 + r0 + q) * ldc + col] = (OutT)v;
    }
  }
}

// ---------------------------------------------------------------- attention scores/softmax/wc
// one block per (t,b): scores[s] = ctx[s,b,:].q ; softmax ; wc = a @ ctx[:,b,:]
__global__ __launch_bounds__(256) void attn_kernel(
    const float* __restrict__ Q,   // [4096][1024] f32
    const float* __restrict__ ctx, // context f32 [S=64][B=64][H=1024]
    f16* __restrict__ wc,          // [4096][1024] f16
    float* __restrict__ attn_out) {// [64][64] (t==63 only)
  const int m = blockIdx.x;
  const int b = m & 63;
  const int t = m >> 6;
  const int tid = threadIdx.x;
  const int lane = tid & 63;
  const int w = tid >> 6;
  __shared__ float s_sc[64];
  __shared__ float s_at[64];

  const float* qp = Q + (size_t)m * 1024 + lane * 16;
  float qf[16];
#pragma unroll
  for (int i = 0; i < 4; i++) {
    float4 v = *(const float4*)(qp + i * 4);
    qf[i * 4 + 0] = v.x; qf[i * 4 + 1] = v.y; qf[i * 4 + 2] = v.z; qf[i * 4 + 3] = v.w;
  }

  // scores: wave w handles s in [w*16, w*16+16)
  for (int si = 0; si < 16; si++) {
    int s = w * 16 + si;
    const float* cp = ctx + ((size_t)s * 64 + b) * 1024 + lane * 16;
    float d = 0.f;
#pragma unroll
    for (int i = 0; i < 4; i++) {
      float4 v = *(const float4*)(cp + i * 4);
      d += v.x * qf[i * 4] + v.y * qf[i * 4 + 1] + v.z * qf[i * 4 + 2] + v.w * qf[i * 4 + 3];
    }
#pragma unroll
    for (int off = 32; off > 0; off >>= 1) d += __shfl_down(d, off, 64);
    if (lane == 0) s_sc[s] = d;
  }
  __syncthreads();
  if (w == 0) {
    float v = s_sc[lane];
    float mx = v;
#pragma unroll
    for (int off = 32; off > 0; off >>= 1) mx = fmaxf(mx, __shfl_xor(mx, off, 64));
    float e = __expf(v - mx);
    float sm = e;
#pragma unroll
    for (int off = 32; off > 0; off >>= 1) sm += __shfl_xor(sm, off, 64);
    float a = e / sm;
    s_at[lane] = a;
    if (t == 63) attn_out[b * 64 + lane] = a;
  }
  __syncthreads();
#pragma unroll
  for (int rep = 0; rep < 4; rep++) {
    int h = rep * 256 + tid;
    float acc = 0.f;
    for (int s = 0; s < 64; s++)
      acc += s_at[s] * ctx[((size_t)s * 64 + b) * 1024 + h];
    wc[(size_t)m * 1024 + h] = (f16)acc;
  }
}

// ---------------------------------------------------------------- launch
extern "C" void kernel_launch(void* const* d_in, const int* in_sizes, int n_in,
                              void* d_out, int out_size, void* d_ws, size_t ws_size,
                              hipStream_t stream) {
  const int*   input = (const int*)d_in[0];
  const float* h0    = (const float*)d_in[1];
  const float* c0    = (const float*)d_in[2];
  const float* ctx   = (const float*)d_in[3];
  const float* emb   = (const float*)d_in[4];
  const float* w_ih  = (const float*)d_in[5];
  const float* w_hh  = (const float*)d_in[6];
  const float* b_ih  = (const float*)d_in[7];
  const float* b_hh  = (const float*)d_in[8];
  const float* w_in  = (const float*)d_in[9];
  const float* w_out = (const float*)d_in[10];
  float* out = (float*)d_out;

  char* ws = (char*)d_ws;
  size_t off = 0;
  auto alloc = [&](size_t bytes) {
    char* p = ws + off;
    off += (bytes + 255) & ~(size_t)255;
    return p;
  };
  f16*   h2hist = (f16*)alloc((size_t)65 * 65536 * 2);     // slot0=init, slot t+1=h2_t
  f16*   h1buf  = (f16*)alloc((size_t)2 * 65536 * 2);      // layer-1 h ping-pong
  float* Q      = (float*)alloc((size_t)4096 * 1024 * 4);  // f32 for attention accuracy
  f16*   wc     = (f16*)alloc((size_t)4096 * 1024 * 2);
  f16*   xg     = (f16*)alloc((size_t)4096 * 1024 * 2);    // gathered emb rows
  f16*   winh   = (f16*)alloc((size_t)1024 * 1024 * 2);
  f16*   wouth  = (f16*)alloc((size_t)1024 * 2048 * 2);
  unsigned* bar = (unsigned*)alloc(256);                   // grid-barrier counter

  float* outs = out;                              // [T*B][1024]
  float* hf   = out + (size_t)4096 * 1024;        // [2][64][1024]
  float* cf   = hf + 131072;
  float* attn = cf + 131072;                      // [64][64]

  // ---- small weight converts (only the ones still needed by K3/K5) + emb gather
  f2h_kernel<<<1024, 256, 0, stream>>>(w_in, winh);   // 1024*1024
  f2h_kernel<<<2048, 256, 0, stream>>>(w_out, wouth); // 1024*2048
  gather_rows<<<4096, 256, 0, stream>>>(emb, input, xg);
  init_h<<<256, 256, 0, stream>>>(h0, h1buf, h2hist, bar);

  // ---- K2: entire 64-step 2-layer LSTM in ONE cooperative kernel.
  // Weights live in LDS; cross-phase h traffic via agent-scope (sc1) atomics;
  // custom LLC-counter barrier instead of cg::grid.sync (~50us/phase measured).
  {
    void* args[] = {(void*)&w_ih, (void*)&w_hh, (void*)&b_ih, (void*)&b_hh,
                    (void*)&c0, (void*)&xg, (void*)&h1buf, (void*)&h2hist,
                    (void*)&hf, (void*)&cf, (void*)&bar};
    hipLaunchCooperativeKernel(lstm_persistent, dim3(256), dim3(512), args, 0, stream);
  }

  // K3: Q = H2_all @ w_in^T   [M=4096,N=1024,K=1024], f32 out
  gemm_simple<float><<<dim3(16, 64), 256, 0, stream>>>(h2hist + 65536, nullptr,
      winh, nullptr, nullptr, Q, 1024, 1024, 1024, 0);

  // K4: scores -> softmax -> weighted context (+ final-step attention output), all f32
  attn_kernel<<<4096, 256, 0, stream>>>(Q, ctx, wc, attn);

  // K5: outs = tanh([wc | H2_all] @ w_out^T)   [M=4096,N=1024,K=2048], f32 out
  gemm_simple<float><<<dim3(16, 64), 256, 0, stream>>>(wc, h2hist + 65536,
      wouth, nullptr, nullptr, outs, 1024, 1024, 2048, 1);
}

// Round 3
// 1987.514 us; speedup vs baseline: 1.8652x; 1.0769x over previous
//
#include <hip/hip_runtime.h>

typedef _Float16 f16;
typedef __attribute__((ext_vector_type(4))) _Float16 f16x4;
typedef __attribute__((ext_vector_type(8))) _Float16 f16x8;
typedef __attribute__((ext_vector_type(4))) float f32x4;

// ---------------------------------------------------------------- helpers
__device__ __forceinline__ float fast_sig(float x) { return 1.f / (1.f + __expf(-x)); }
// tanh via 1 - 2/(e^{2x}+1): saturates cleanly to +/-1, no NaN at extremes
__device__ __forceinline__ float fast_tanh(float x) {
  float e = __expf(2.f * x);
  return 1.f - 2.f / (e + 1.f);
}

// agent-scope (device-coherent, sc1) 16B load as two 8B relaxed atomic loads:
// bypasses the per-XCD L2 so cross-XCD h-vectors are read fresh from LLC
// without any cache-maintenance fence.
__device__ __forceinline__ f16x8 ld_dev(const f16* p) {
  unsigned long long u0 = __hip_atomic_load((const unsigned long long*)p,
                                            __ATOMIC_RELAXED, __HIP_MEMORY_SCOPE_AGENT);
  unsigned long long u1 = __hip_atomic_load((const unsigned long long*)p + 1,
                                            __ATOMIC_RELAXED, __HIP_MEMORY_SCOPE_AGENT);
  union { unsigned long long u; f16x4 h; } a, b;
  a.u = u0; b.u = u1;
  return __builtin_shufflevector(a.h, b.h, 0, 1, 2, 3, 4, 5, 6, 7);
}

// ---------------------------------------------------------------- f32 -> f16 convert
__global__ __launch_bounds__(256) void f2h_kernel(const float* __restrict__ src,
                                                  f16* __restrict__ dst) {
  size_t i = ((size_t)blockIdx.x * 256 + threadIdx.x) * 4;
  float4 v = *(const float4*)(src + i);
  dst[i + 0] = (f16)v.x;
  dst[i + 1] = (f16)v.y;
  dst[i + 2] = (f16)v.z;
  dst[i + 3] = (f16)v.w;
}

// gather embedding rows: xg[m,:] = (f16)emb[ids[m],:]   (one block per m, H=1024)
__global__ __launch_bounds__(256) void gather_rows(const float* __restrict__ emb,
                                                   const int* __restrict__ ids,
                                                   f16* __restrict__ xg) {
  int m = blockIdx.x;
  int i = threadIdx.x * 4;
  const float* src = emb + (size_t)ids[m] * 1024 + i;
  float4 v = *(const float4*)src;
  f16* d = xg + (size_t)m * 1024 + i;
  d[0] = (f16)v.x; d[1] = (f16)v.y; d[2] = (f16)v.z; d[3] = (f16)v.w;
}

// ---------------------------------------------------------------- h-state init + flag reset
__global__ __launch_bounds__(256) void init_h(const float* __restrict__ h0,
                                              f16* __restrict__ h1slot0,
                                              f16* __restrict__ h2slot0,
                                              unsigned* __restrict__ flags) {
  int i = blockIdx.x * 256 + threadIdx.x;  // grid 256 -> 65536
  h1slot0[i] = (f16)h0[i];
  h2slot0[i] = (f16)h0[65536 + i];
  if (i < 4096) flags[i] = 0;              // 256 flags, 64B-padded (stride 16 u32)
}

// ---------------------------------------------------------------- persistent 2-layer LSTM
// One cooperative launch runs all 64 timesteps. 256 blocks x 512 threads (8 waves),
// block p owns hidden units [4p,4p+4) of BOTH layers: 16 gate-rows x 4 matrices
// (Wih1,Whh1,Wih2,Whh2) = 128 KB f16 staged into LDS ONCE.
// Software pipeline: phase t computes layer1_t and layer2_{t-1} in ONE merged
// K-loop (shared h1 operand loaded once).
// Cross-block sync evolution (measured):
//   cg::grid.sync            ~46 us/phase (device fence -> L2 writeback/inv)
//   single LLC atomic counter ~22 us/phase (256 same-line RMWs serialize ~180cy each)
//   THIS: store/poll flags    (no RMW: 256 parallel stores to distinct lines,
//         every block polls all flags read-only; reads don't serialize)
// All cross-phase data (h1buf, h2hist) moves via agent-scope (sc1) relaxed
// atomics (write through to / read from LLC), so no cache maintenance needed;
// __syncthreads' vmcnt drain commits stores before the flag publish.
__global__ __launch_bounds__(512, 1) void lstm_persistent(
    const float* __restrict__ w_ih, const float* __restrict__ w_hh,  // [2][4096][1024] f32
    const float* __restrict__ b_ih, const float* __restrict__ b_hh,  // [2][4096] f32
    const float* __restrict__ c0,                                    // [2][64][1024] f32
    const f16* __restrict__ xg,                                      // [4096][1024] f16
    f16* __restrict__ h1buf,                                         // 2 ping-pong slots
    f16* __restrict__ h2hist,                                        // 65 slots (slot0 = init)
    float* __restrict__ hf, float* __restrict__ cf,                  // [2][64][1024] f32
    unsigned* __restrict__ flags) {                                  // [256] stride-16 u32
  __shared__ f16 wlds[65536];               // 4 matrices x 2048 slots x 8 f16 = 128 KB
  __shared__ float red1[2048], red2[2048];  // [wave][16m][16n] partials, 8 KB each
  __shared__ float bsum[32];                // b_ih+b_hh for this block's 16 rows x 2 layers
  const int p = blockIdx.x;
  const int tid = threadIdx.x;
  const int lane = tid & 63, w = tid >> 6;
  const int mt = w & 3, kh = w >> 2;        // wave = (batch-tile, K-half)
  const int am = mt * 16 + (lane & 15);     // A-fragment batch row
  const int kq = (lane >> 4) * 8;

  // ---- one-time staging: 8192 slots / 512 threads = 16 each
  for (int s = tid; s < 8192; s += 512) {
    const int mat = s >> 11, sl = s & 2047;       // mat: 0=Wih1 1=Whh1 2=Wih2 3=Whh2
    const int ln = sl & 63, ks = sl >> 6;
    const int n = ln & 15;                        // n = gate*4 + unit_local
    const int row = (n >> 2) * 1024 + p * 4 + (n & 3) + ((mat >= 2) ? 4096 : 0);
    const int k = ks * 32 + (ln >> 4) * 8;
    const float* src = ((mat & 1) ? w_hh : w_ih) + (size_t)row * 1024 + k;
    float4 v0 = *(const float4*)src;
    float4 v1 = *(const float4*)(src + 4);
    f16x8 hv = {(f16)v0.x, (f16)v0.y, (f16)v0.z, (f16)v0.w,
                (f16)v1.x, (f16)v1.y, (f16)v1.z, (f16)v1.w};
    *(f16x8*)(wlds + (size_t)mat * 16384 + (size_t)sl * 8) = hv;
  }
  if (tid < 32) {
    int l = tid >> 4, n = tid & 15;
    int row = l * 4096 + (n >> 2) * 1024 + p * 4 + (n & 3);
    bsum[tid] = b_ih[row] + b_hh[row];
  }
  float creg;
  {
    int q = tid & 255;
    size_t idx = (size_t)(q >> 2) * 1024 + p * 4 + (q & 3);
    creg = (tid < 256) ? c0[idx] : c0[65536 + idx];
  }
  __syncthreads();

  for (int t = 0; t <= 64; ++t) {
    const f16* h1p = h1buf + (size_t)(t & 1) * 65536;  // h1_{t-1}
    // clamped addresses so edge phases stay straight-line (MFMA predicated off)
    const int tx = (t < 64) ? t : 63;
    const int t2 = (t > 0) ? t - 1 : 0;
    const f16* xrow = xg + ((size_t)tx * 64 + am) * 1024;
    const f16* hrow = h1p + (size_t)am * 1024;
    const f16* h2row = h2hist + ((size_t)t2 * 64 + am) * 1024;

    f32x4 acc1 = {0.f, 0.f, 0.f, 0.f};
    f32x4 acc2 = {0.f, 0.f, 0.f, 0.f};
#pragma unroll 4
    for (int ks = kh * 16; ks < kh * 16 + 16; ++ks) {
      int k = ks * 32 + kq;
      f16x8 xv = *(const f16x8*)(xrow + k);   // xg: immutable, normal cached load
      f16x8 hv = ld_dev(hrow + k);            // cross-phase: agent-scope
      f16x8 h2v = ld_dev(h2row + k);          // cross-phase: agent-scope
      f16x8 b0 = *(const f16x8*)(wlds + (size_t)ks * 512 + lane * 8);
      f16x8 b1 = *(const f16x8*)(wlds + 16384 + (size_t)ks * 512 + lane * 8);
      f16x8 b2 = *(const f16x8*)(wlds + 32768 + (size_t)ks * 512 + lane * 8);
      f16x8 b3 = *(const f16x8*)(wlds + 49152 + (size_t)ks * 512 + lane * 8);
      if (t < 64) {  // layer-1 gates, timestep t
        acc1 = __builtin_amdgcn_mfma_f32_16x16x32_f16(xv, b0, acc1, 0, 0, 0);
        acc1 = __builtin_amdgcn_mfma_f32_16x16x32_f16(hv, b1, acc1, 0, 0, 0);
      }
      if (t > 0) {   // layer-2 gates, timestep t-1
        acc2 = __builtin_amdgcn_mfma_f32_16x16x32_f16(hv, b2, acc2, 0, 0, 0);
        acc2 = __builtin_amdgcn_mfma_f32_16x16x32_f16(h2v, b3, acc2, 0, 0, 0);
      }
    }
    if (t < 64) {
#pragma unroll
      for (int q = 0; q < 4; q++)
        red1[w * 256 + ((lane >> 4) * 4 + q) * 16 + (lane & 15)] = acc1[q];
    }
    if (t > 0) {
#pragma unroll
      for (int q = 0; q < 4; q++)
        red2[w * 256 + ((lane >> 4) * 4 + q) * 16 + (lane & 15)] = acc2[q];
    }
    __syncthreads();

    // ---- elementwise: threads 0-255 -> layer1, 256-511 -> layer2
    if (t < 64 && tid < 256) {
      const int b = tid >> 2, ul = tid & 3;
      const int mrow = (b & 15) * 16, mtb = (b >> 4) * 256;
      float g4[4];
#pragma unroll
      for (int g = 0; g < 4; g++) {
        int n = g * 4 + ul;
        g4[g] = red1[mtb + mrow + n] + red1[1024 + mtb + mrow + n] + bsum[n];
      }
      float cn = fast_sig(g4[1]) * creg + fast_sig(g4[0]) * fast_tanh(g4[2]);
      float hn = fast_sig(g4[3]) * fast_tanh(cn);
      creg = cn;
      const int u = p * 4 + ul;
      if (t == 63) {
        hf[(size_t)b * 1024 + u] = hn;
        cf[(size_t)b * 1024 + u] = cn;
      }
      // pack 4 units (ul=0..3, same wave) -> one 8B agent-scope store
      float h1v = __shfl_down(hn, 1, 64);
      float h2s = __shfl_down(hn, 2, 64);
      float h3v = __shfl_down(hn, 3, 64);
      if (ul == 0) {
        union { f16x4 h; unsigned long long u64; } pk;
        pk.h = (f16x4){(f16)hn, (f16)h1v, (f16)h2s, (f16)h3v};
        f16* dst = h1buf + (size_t)((t & 1) ^ 1) * 65536 + (size_t)b * 1024 + p * 4;
        __hip_atomic_store((unsigned long long*)dst, pk.u64,
                           __ATOMIC_RELAXED, __HIP_MEMORY_SCOPE_AGENT);
      }
    }
    if (t > 0 && tid >= 256) {
      const int q = tid & 255;
      const int b = q >> 2, ul = q & 3;
      const int mrow = (b & 15) * 16, mtb = (b >> 4) * 256;
      float g4[4];
#pragma unroll
      for (int g = 0; g < 4; g++) {
        int n = g * 4 + ul;
        g4[g] = red2[mtb + mrow + n] + red2[1024 + mtb + mrow + n] + bsum[16 + n];
      }
      float cn = fast_sig(g4[1]) * creg + fast_sig(g4[0]) * fast_tanh(g4[2]);
      float hn = fast_sig(g4[3]) * fast_tanh(cn);
      creg = cn;
      const int u = p * 4 + ul;
      if (t == 64) {
        hf[65536 + (size_t)b * 1024 + u] = hn;
        cf[65536 + (size_t)b * 1024 + u] = cn;
      }
      float h1v = __shfl_down(hn, 1, 64);
      float h2s = __shfl_down(hn, 2, 64);
      float h3v = __shfl_down(hn, 3, 64);
      if (ul == 0) {
        union { f16x4 h; unsigned long long u64; } pk;
        pk.h = (f16x4){(f16)hn, (f16)h1v, (f16)h2s, (f16)h3v};
        f16* dst = h2hist + (size_t)t * 65536 + (size_t)b * 1024 + p * 4;
        __hip_atomic_store((unsigned long long*)dst, pk.u64,
                           __ATOMIC_RELAXED, __HIP_MEMORY_SCOPE_AGENT);
      }
    }

    if (t < 64) {
      // store/poll flag barrier (no RMW):
      // __syncthreads drains every wave's vmcnt -> all agent stores at LLC.
      __syncthreads();
      const unsigned epoch = (unsigned)(t + 1);
      if (w == 0) {
        if (lane == 0)
          __hip_atomic_store(flags + (size_t)p * 16, epoch,
                             __ATOMIC_RELAXED, __HIP_MEMORY_SCOPE_AGENT);
        for (;;) {  // each lane watches 4 blocks' flags (64B-padded lines)
          bool ok = true;
#pragma unroll
          for (int j = 0; j < 4; j++) {
            unsigned v = __hip_atomic_load(flags + (size_t)(lane * 4 + j) * 16,
                                           __ATOMIC_RELAXED, __HIP_MEMORY_SCOPE_AGENT);
            ok &= (v >= epoch);
          }
          if (__all(ok)) break;
          __builtin_amdgcn_s_sleep(1);
        }
      }
      __syncthreads();
    }
  }
}

// ---------------------------------------------------------------- simple direct-global GEMM
// C[m,n] = sum_k A[m,k]*B[n,k] (+bias1+bias2)(tanh). A = A1 rows [*,K1] then A2 for k>=K1.
// B row-major [N, Ktot], all f16. Block = 64x64 tile, 4 waves; wave w owns 16 m-rows.
template <typename OutT>
__global__ __launch_bounds__(256) void gemm_simple(
    const f16* __restrict__ A1, const f16* __restrict__ A2,
    const f16* __restrict__ Bm,
    const float* __restrict__ bias1, const float* __restrict__ bias2,
    OutT* __restrict__ C, int ldc,
    int K1, int Ktot, int do_tanh) {
  const int tid = threadIdx.x;
  const int lane = tid & 63;
  const int w = tid >> 6;
  const int m0 = blockIdx.y * 64 + w * 16;  // this wave's 16 m-rows
  const int n0 = blockIdx.x * 64;
  const int am = m0 + (lane & 15);
  const int kq = (lane >> 4) * 8;           // quad's k-offset within a 32-chunk
  const int K2 = Ktot - K1;

  f32x4 acc[4];
#pragma unroll
  for (int j = 0; j < 4; j++) acc[j] = (f32x4){0.f, 0.f, 0.f, 0.f};

  for (int k0 = 0; k0 < Ktot; k0 += 32) {
    int k = k0 + kq;
    f16x8 av;
    if (k < K1)
      av = *(const f16x8*)(A1 + (size_t)am * K1 + k);
    else
      av = *(const f16x8*)(A2 + (size_t)am * K2 + (k - K1));
#pragma unroll
    for (int j = 0; j < 4; j++) {
      f16x8 bv = *(const f16x8*)(Bm + (size_t)(n0 + j * 16 + (lane & 15)) * Ktot + k);
      acc[j] = __builtin_amdgcn_mfma_f32_16x16x32_f16(av, bv, acc[j], 0, 0, 0);
    }
  }

  const int r0 = (lane >> 4) * 4;
  const int cc = lane & 15;
#pragma unroll
  for (int j = 0; j < 4; j++) {
    int col = n0 + j * 16 + cc;
    float bv = 0.f;
    if (bias1) bv += bias1[col];
    if (bias2) bv += bias2[col];
#pragma unroll
    for (int q = 0; q < 4; q++) {
      float v = acc[j][q] + bv;
      if (do_tanh) v = fast_tanh(v);
      C[(size_t)(m0 + r0 + q) * ldc + col] = (OutT)v;
    }
  }
}

// ---------------------------------------------------------------- attention scores/softmax/wc
// one block per (t,b): scores[s] = ctx[s,b,:].q ; softmax ; wc = a @ ctx[:,b,:]
__global__ __launch_bounds__(256) void attn_kernel(
    const float* __restrict__ Q,   // [4096][1024] f32
    const float* __restrict__ ctx, // context f32 [S=64][B=64][H=1024]
    f16* __restrict__ wc,          // [4096][1024] f16
    float* __restrict__ attn_out) {// [64][64] (t==63 only)
  const int m = blockIdx.x;
  const int b = m & 63;
  const int t = m >> 6;
  const int tid = threadIdx.x;
  const int lane = tid & 63;
  const int w = tid >> 6;
  __shared__ float s_sc[64];
  __shared__ float s_at[64];

  const float* qp = Q + (size_t)m * 1024 + lane * 16;
  float qf[16];
#pragma unroll
  for (int i = 0; i < 4; i++) {
    float4 v = *(const float4*)(qp + i * 4);
    qf[i * 4 + 0] = v.x; qf[i * 4 + 1] = v.y; qf[i * 4 + 2] = v.z; qf[i * 4 + 3] = v.w;
  }

  // scores: wave w handles s in [w*16, w*16+16)
  for (int si = 0; si < 16; si++) {
    int s = w * 16 + si;
    const float* cp = ctx + ((size_t)s * 64 + b) * 1024 + lane * 16;
    float d = 0.f;
#pragma unroll
    for (int i = 0; i < 4; i++) {
      float4 v = *(const float4*)(cp + i * 4);
      d += v.x * qf[i * 4] + v.y * qf[i * 4 + 1] + v.z * qf[i * 4 + 2] + v.w * qf[i * 4 + 3];
    }
#pragma unroll
    for (int off = 32; off > 0; off >>= 1) d += __shfl_down(d, off, 64);
    if (lane == 0) s_sc[s] = d;
  }
  __syncthreads();
  if (w == 0) {
    float v = s_sc[lane];
    float mx = v;
#pragma unroll
    for (int off = 32; off > 0; off >>= 1) mx = fmaxf(mx, __shfl_xor(mx, off, 64));
    float e = __expf(v - mx);
    float sm = e;
#pragma unroll
    for (int off = 32; off > 0; off >>= 1) sm += __shfl_xor(sm, off, 64);
    float a = e / sm;
    s_at[lane] = a;
    if (t == 63) attn_out[b * 64 + lane] = a;
  }
  __syncthreads();
#pragma unroll
  for (int rep = 0; rep < 4; rep++) {
    int h = rep * 256 + tid;
    float acc = 0.f;
    for (int s = 0; s < 64; s++)
      acc += s_at[s] * ctx[((size_t)s * 64 + b) * 1024 + h];
    wc[(size_t)m * 1024 + h] = (f16)acc;
  }
}

// ---------------------------------------------------------------- launch
extern "C" void kernel_launch(void* const* d_in, const int* in_sizes, int n_in,
                              void* d_out, int out_size, void* d_ws, size_t ws_size,
                              hipStream_t stream) {
  const int*   input = (const int*)d_in[0];
  const float* h0    = (const float*)d_in[1];
  const float* c0    = (const float*)d_in[2];
  const float* ctx   = (const float*)d_in[3];
  const float* emb   = (const float*)d_in[4];
  const float* w_ih  = (const float*)d_in[5];
  const float* w_hh  = (const float*)d_in[6];
  const float* b_ih  = (const float*)d_in[7];
  const float* b_hh  = (const float*)d_in[8];
  const float* w_in  = (const float*)d_in[9];
  const float* w_out = (const float*)d_in[10];
  float* out = (float*)d_out;

  char* ws = (char*)d_ws;
  size_t off = 0;
  auto alloc = [&](size_t bytes) {
    char* p = ws + off;
    off += (bytes + 255) & ~(size_t)255;
    return p;
  };
  f16*   h2hist = (f16*)alloc((size_t)65 * 65536 * 2);     // slot0=init, slot t+1=h2_t
  f16*   h1buf  = (f16*)alloc((size_t)2 * 65536 * 2);      // layer-1 h ping-pong
  float* Q      = (float*)alloc((size_t)4096 * 1024 * 4);  // f32 for attention accuracy
  f16*   wc     = (f16*)alloc((size_t)4096 * 1024 * 2);
  f16*   xg     = (f16*)alloc((size_t)4096 * 1024 * 2);    // gathered emb rows
  f16*   winh   = (f16*)alloc((size_t)1024 * 1024 * 2);
  f16*   wouth  = (f16*)alloc((size_t)1024 * 2048 * 2);
  unsigned* flags = (unsigned*)alloc(16384);               // 256 flags, 64B-padded

  float* outs = out;                              // [T*B][1024]
  float* hf   = out + (size_t)4096 * 1024;        // [2][64][1024]
  float* cf   = hf + 131072;
  float* attn = cf + 131072;                      // [64][64]

  // ---- small weight converts (only the ones still needed by K3/K5) + emb gather
  f2h_kernel<<<1024, 256, 0, stream>>>(w_in, winh);   // 1024*1024
  f2h_kernel<<<2048, 256, 0, stream>>>(w_out, wouth); // 1024*2048
  gather_rows<<<4096, 256, 0, stream>>>(emb, input, xg);
  init_h<<<256, 256, 0, stream>>>(h0, h1buf, h2hist, flags);

  // ---- K2: entire 64-step 2-layer LSTM in ONE cooperative kernel.
  // Weights live in LDS; cross-phase h traffic via agent-scope (sc1) atomics;
  // store/poll flag barrier (no same-line RMW serialization).
  {
    void* args[] = {(void*)&w_ih, (void*)&w_hh, (void*)&b_ih, (void*)&b_hh,
                    (void*)&c0, (void*)&xg, (void*)&h1buf, (void*)&h2hist,
                    (void*)&hf, (void*)&cf, (void*)&flags};
    hipLaunchCooperativeKernel(lstm_persistent, dim3(256), dim3(512), args, 0, stream);
  }

  // K3: Q = H2_all @ w_in^T   [M=4096,N=1024,K=1024], f32 out
  gemm_simple<float><<<dim3(16, 64), 256, 0, stream>>>(h2hist + 65536, nullptr,
      winh, nullptr, nullptr, Q, 1024, 1024, 1024, 0);

  // K4: scores -> softmax -> weighted context (+ final-step attention output), all f32
  attn_kernel<<<4096, 256, 0, stream>>>(Q, ctx, wc, attn);

  // K5: outs = tanh([wc | H2_all] @ w_out^T)   [M=4096,N=1024,K=2048], f32 out
  gemm_simple<float><<<dim3(16, 64), 256, 0, stream>>>(wc, h2hist + 65536,
      wouth, nullptr, nullptr, outs, 1024, 1024, 2048, 1);
}

// Round 4
// 1602.511 us; speedup vs baseline: 2.3133x; 1.2403x over previous
//
#include <hip/hip_runtime.h>

typedef _Float16 f16;
typedef __attribute__((ext_vector_type(4))) _Float16 f16x4;
typedef __attribute__((ext_vector_type(8))) _Float16 f16x8;
typedef __attribute__((ext_vector_type(4))) float f32x4;

// ---------------------------------------------------------------- helpers
__device__ __forceinline__ float fast_sig(float x) { return 1.f / (1.f + __expf(-x)); }
// tanh via 1 - 2/(e^{2x}+1): saturates cleanly to +/-1, no NaN at extremes
__device__ __forceinline__ float fast_tanh(float x) {
  float e = __expf(2.f * x);
  return 1.f - 2.f / (e + 1.f);
}

// ---------------------------------------------------------------- f32 -> f16 convert
__global__ __launch_bounds__(256) void f2h_kernel(const float* __restrict__ src,
                                                  f16* __restrict__ dst) {
  size_t i = ((size_t)blockIdx.x * 256 + threadIdx.x) * 4;
  float4 v = *(const float4*)(src + i);
  dst[i + 0] = (f16)v.x;
  dst[i + 1] = (f16)v.y;
  dst[i + 2] = (f16)v.z;
  dst[i + 3] = (f16)v.w;
}

// gather embedding rows: xg[m,:] = (f16)emb[ids[m],:]   (one block per m, H=1024)
__global__ __launch_bounds__(256) void gather_rows(const float* __restrict__ emb,
                                                   const int* __restrict__ ids,
                                                   f16* __restrict__ xg) {
  int m = blockIdx.x;
  int i = threadIdx.x * 4;
  const float* src = emb + (size_t)ids[m] * 1024 + i;
  float4 v = *(const float4*)src;
  f16* d = xg + (size_t)m * 1024 + i;
  d[0] = (f16)v.x; d[1] = (f16)v.y; d[2] = (f16)v.z; d[3] = (f16)v.w;
}

// ---------------------------------------------------------------- h-state init + flag reset
__global__ __launch_bounds__(256) void init_h(const float* __restrict__ h0,
                                              f16* __restrict__ h1slot0,
                                              f16* __restrict__ h2slot0,
                                              unsigned* __restrict__ flags) {
  int i = blockIdx.x * 256 + threadIdx.x;  // grid 256 -> 65536
  h1slot0[i] = (f16)h0[i];
  h2slot0[i] = (f16)h0[65536 + i];
  if (i < 4096) flags[i] = 0;              // 256 flags, 64B-padded (stride 16 u32)
}

// ---------------------------------------------------------------- persistent 2-layer LSTM
// One cooperative launch runs all 64 timesteps. 256 blocks x 512 threads (8 waves),
// block p owns hidden units [4p,4p+4) of BOTH layers: 16 gate-rows x 4 matrices
// (Wih1,Whh1,Wih2,Whh2) = 128 KB f16 staged into LDS ONCE.
// Phase t computes layer1_t and layer2_{t-1} in one merged pass.
// Sync evolution (measured): cg::grid.sync ~46us/phase; single-line LLC atomic
// ~22us/phase; store/poll flags ~21.8us/phase -> barrier was NOT the cost.
// The cost was sc1 load latency with ~no MLP (64 serial-ish 8B atomic loads/lane,
// ~800cy LLC latency, 2 waves/SIMD). THIS version: batch-issue 32 inline-asm
// global_load_dwordx4 sc1 per lane (base + imm offset, no per-load addr math),
// then one counted drain -> 32-deep MLP; xg MFMA pass runs under the burst.
__global__ __launch_bounds__(512, 1) void lstm_persistent(
    const float* __restrict__ w_ih, const float* __restrict__ w_hh,  // [2][4096][1024] f32
    const float* __restrict__ b_ih, const float* __restrict__ b_hh,  // [2][4096] f32
    const float* __restrict__ c0,                                    // [2][64][1024] f32
    const f16* __restrict__ xg,                                      // [4096][1024] f16
    f16* __restrict__ h1buf,                                         // 2 ping-pong slots
    f16* __restrict__ h2hist,                                        // 65 slots (slot0 = init)
    float* __restrict__ hf, float* __restrict__ cf,                  // [2][64][1024] f32
    unsigned* __restrict__ flags) {                                  // [256] stride-16 u32
  __shared__ f16 wlds[65536];               // 4 matrices x 2048 slots x 8 f16 = 128 KB
  __shared__ float red1[2048], red2[2048];  // [wave][16m][16n] partials, 8 KB each
  __shared__ float bsum[32];                // b_ih+b_hh for this block's 16 rows x 2 layers
  const int p = blockIdx.x;
  const int tid = threadIdx.x;
  const int lane = tid & 63, w = tid >> 6;
  const int mt = w & 3, kh = w >> 2;        // wave = (batch-tile, K-half)
  const int am = mt * 16 + (lane & 15);     // A-fragment batch row
  const int kq = (lane >> 4) * 8;

  // ---- one-time staging: 8192 slots / 512 threads = 16 each
  for (int s = tid; s < 8192; s += 512) {
    const int mat = s >> 11, sl = s & 2047;       // mat: 0=Wih1 1=Whh1 2=Wih2 3=Whh2
    const int ln = sl & 63, ks = sl >> 6;
    const int n = ln & 15;                        // n = gate*4 + unit_local
    const int row = (n >> 2) * 1024 + p * 4 + (n & 3) + ((mat >= 2) ? 4096 : 0);
    const int k = ks * 32 + (ln >> 4) * 8;
    const float* src = ((mat & 1) ? w_hh : w_ih) + (size_t)row * 1024 + k;
    float4 v0 = *(const float4*)src;
    float4 v1 = *(const float4*)(src + 4);
    f16x8 hv = {(f16)v0.x, (f16)v0.y, (f16)v0.z, (f16)v0.w,
                (f16)v1.x, (f16)v1.y, (f16)v1.z, (f16)v1.w};
    *(f16x8*)(wlds + (size_t)mat * 16384 + (size_t)sl * 8) = hv;
  }
  if (tid < 32) {
    int l = tid >> 4, n = tid & 15;
    int row = l * 4096 + (n >> 2) * 1024 + p * 4 + (n & 3);
    bsum[tid] = b_ih[row] + b_hh[row];
  }
  float creg;
  {
    int q = tid & 255;
    size_t idx = (size_t)(q >> 2) * 1024 + p * 4 + (q & 3);
    creg = (tid < 256) ? c0[idx] : c0[65536 + idx];
  }
  __syncthreads();

  for (int t = 0; t <= 64; ++t) {
    const f16* h1p = h1buf + (size_t)(t & 1) * 65536;  // h1_{t-1}
    // clamped addresses so edge phases stay straight-line (MFMA predicated off)
    const int tx = (t < 64) ? t : 63;
    const int t2 = (t > 0) ? t - 1 : 0;
    // per-lane k-base for this wave: k = ks*32 + kq, ks in [kh*16, kh*16+16)
    const f16* xrow  = xg + ((size_t)tx * 64 + am) * 1024 + kh * 512 + kq;
    const f16* hrow  = h1p + (size_t)am * 1024 + kh * 512 + kq;
    const f16* h2row = h2hist + ((size_t)t2 * 64 + am) * 1024 + kh * 512 + kq;

    // ---- batch-issue 32 sc1 loads (16B each, imm offsets 0..960): 32-deep MLP.
    // sc1 = agent-scope: bypasses stale per-XCD L2, served by LLC.
    f16x8 h1r[16], h2r[16];
#pragma unroll
    for (int i = 0; i < 16; ++i)
      asm volatile("global_load_dwordx4 %0, %1, off offset:%c2 sc1"
                   : "=v"(h1r[i]) : "v"(hrow), "i"(i * 64));
#pragma unroll
    for (int i = 0; i < 16; ++i)
      asm volatile("global_load_dwordx4 %0, %1, off offset:%c2 sc1"
                   : "=v"(h2r[i]) : "v"(h2row), "i"(i * 64));

    f32x4 acc1 = {0.f, 0.f, 0.f, 0.f};
    f32x4 acc2 = {0.f, 0.f, 0.f, 0.f};

    // ---- pass 1 (overlaps the sc1 burst): layer-1 x-part, compiler-managed loads
    if (t < 64) {
#pragma unroll
      for (int i = 0; i < 16; ++i) {
        const int ks = kh * 16 + i;
        f16x8 xv = *(const f16x8*)(xrow + i * 32);
        f16x8 b0 = *(const f16x8*)(wlds + (size_t)ks * 512 + lane * 8);
        acc1 = __builtin_amdgcn_mfma_f32_16x16x32_f16(xv, b0, acc1, 0, 0, 0);
      }
    }

    // ---- drain the sc1 burst, then consume from registers
    asm volatile("s_waitcnt vmcnt(0)" ::: "memory");
    __builtin_amdgcn_sched_barrier(0);
#pragma unroll
    for (int i = 0; i < 16; ++i) {
      const int ks = kh * 16 + i;
      f16x8 b1 = *(const f16x8*)(wlds + 16384 + (size_t)ks * 512 + lane * 8);
      f16x8 b2 = *(const f16x8*)(wlds + 32768 + (size_t)ks * 512 + lane * 8);
      f16x8 b3 = *(const f16x8*)(wlds + 49152 + (size_t)ks * 512 + lane * 8);
      if (t < 64)
        acc1 = __builtin_amdgcn_mfma_f32_16x16x32_f16(h1r[i], b1, acc1, 0, 0, 0);
      if (t > 0) {
        acc2 = __builtin_amdgcn_mfma_f32_16x16x32_f16(h1r[i], b2, acc2, 0, 0, 0);
        acc2 = __builtin_amdgcn_mfma_f32_16x16x32_f16(h2r[i], b3, acc2, 0, 0, 0);
      }
    }

    if (t < 64) {
#pragma unroll
      for (int q = 0; q < 4; q++)
        red1[w * 256 + ((lane >> 4) * 4 + q) * 16 + (lane & 15)] = acc1[q];
    }
    if (t > 0) {
#pragma unroll
      for (int q = 0; q < 4; q++)
        red2[w * 256 + ((lane >> 4) * 4 + q) * 16 + (lane & 15)] = acc2[q];
    }
    __syncthreads();

    // ---- elementwise: threads 0-255 -> layer1, 256-511 -> layer2
    if (t < 64 && tid < 256) {
      const int b = tid >> 2, ul = tid & 3;
      const int mrow = (b & 15) * 16, mtb = (b >> 4) * 256;
      float g4[4];
#pragma unroll
      for (int g = 0; g < 4; g++) {
        int n = g * 4 + ul;
        g4[g] = red1[mtb + mrow + n] + red1[1024 + mtb + mrow + n] + bsum[n];
      }
      float cn = fast_sig(g4[1]) * creg + fast_sig(g4[0]) * fast_tanh(g4[2]);
      float hn = fast_sig(g4[3]) * fast_tanh(cn);
      creg = cn;
      const int u = p * 4 + ul;
      if (t == 63) {
        hf[(size_t)b * 1024 + u] = hn;
        cf[(size_t)b * 1024 + u] = cn;
      }
      // pack 4 units (ul=0..3, same wave) -> one 8B agent-scope store
      float h1v = __shfl_down(hn, 1, 64);
      float h2s = __shfl_down(hn, 2, 64);
      float h3v = __shfl_down(hn, 3, 64);
      if (ul == 0) {
        union { f16x4 h; unsigned long long u64; } pk;
        pk.h = (f16x4){(f16)hn, (f16)h1v, (f16)h2s, (f16)h3v};
        f16* dst = h1buf + (size_t)((t & 1) ^ 1) * 65536 + (size_t)b * 1024 + p * 4;
        __hip_atomic_store((unsigned long long*)dst, pk.u64,
                           __ATOMIC_RELAXED, __HIP_MEMORY_SCOPE_AGENT);
      }
    }
    if (t > 0 && tid >= 256) {
      const int q = tid & 255;
      const int b = q >> 2, ul = q & 3;
      const int mrow = (b & 15) * 16, mtb = (b >> 4) * 256;
      float g4[4];
#pragma unroll
      for (int g = 0; g < 4; g++) {
        int n = g * 4 + ul;
        g4[g] = red2[mtb + mrow + n] + red2[1024 + mtb + mrow + n] + bsum[16 + n];
      }
      float cn = fast_sig(g4[1]) * creg + fast_sig(g4[0]) * fast_tanh(g4[2]);
      float hn = fast_sig(g4[3]) * fast_tanh(cn);
      creg = cn;
      const int u = p * 4 + ul;
      if (t == 64) {
        hf[65536 + (size_t)b * 1024 + u] = hn;
        cf[65536 + (size_t)b * 1024 + u] = cn;
      }
      float h1v = __shfl_down(hn, 1, 64);
      float h2s = __shfl_down(hn, 2, 64);
      float h3v = __shfl_down(hn, 3, 64);
      if (ul == 0) {
        union { f16x4 h; unsigned long long u64; } pk;
        pk.h = (f16x4){(f16)hn, (f16)h1v, (f16)h2s, (f16)h3v};
        f16* dst = h2hist + (size_t)t * 65536 + (size_t)b * 1024 + p * 4;
        __hip_atomic_store((unsigned long long*)dst, pk.u64,
                           __ATOMIC_RELAXED, __HIP_MEMORY_SCOPE_AGENT);
      }
    }

    if (t < 64) {
      // store/poll flag barrier (no RMW):
      // __syncthreads drains every wave's vmcnt -> all agent stores at LLC.
      __syncthreads();
      const unsigned epoch = (unsigned)(t + 1);
      if (w == 0) {
        if (lane == 0)
          __hip_atomic_store(flags + (size_t)p * 16, epoch,
                             __ATOMIC_RELAXED, __HIP_MEMORY_SCOPE_AGENT);
        for (;;) {  // each lane watches 4 blocks' flags (64B-padded lines)
          bool ok = true;
#pragma unroll
          for (int j = 0; j < 4; j++) {
            unsigned v = __hip_atomic_load(flags + (size_t)(lane * 4 + j) * 16,
                                           __ATOMIC_RELAXED, __HIP_MEMORY_SCOPE_AGENT);
            ok &= (v >= epoch);
          }
          if (__all(ok)) break;
          __builtin_amdgcn_s_sleep(1);
        }
      }
      __syncthreads();
    }
  }
}

// ---------------------------------------------------------------- simple direct-global GEMM
// C[m,n] = sum_k A[m,k]*B[n,k] (+bias1+bias2)(tanh). A = A1 rows [*,K1] then A2 for k>=K1.
// B row-major [N, Ktot], all f16. Block = 64x64 tile, 4 waves; wave w owns 16 m-rows.
template <typename OutT>
__global__ __launch_bounds__(256) void gemm_simple(
    const f16* __restrict__ A1, const f16* __restrict__ A2,
    const f16* __restrict__ Bm,
    const float* __restrict__ bias1, const float* __restrict__ bias2,
    OutT* __restrict__ C, int ldc,
    int K1, int Ktot, int do_tanh) {
  const int tid = threadIdx.x;
  const int lane = tid & 63;
  const int w = tid >> 6;
  const int m0 = blockIdx.y * 64 + w * 16;  // this wave's 16 m-rows
  const int n0 = blockIdx.x * 64;
  const int am = m0 + (lane & 15);
  const int kq = (lane >> 4) * 8;           // quad's k-offset within a 32-chunk
  const int K2 = Ktot - K1;

  f32x4 acc[4];
#pragma unroll
  for (int j = 0; j < 4; j++) acc[j] = (f32x4){0.f, 0.f, 0.f, 0.f};

  for (int k0 = 0; k0 < Ktot; k0 += 32) {
    int k = k0 + kq;
    f16x8 av;
    if (k < K1)
      av = *(const f16x8*)(A1 + (size_t)am * K1 + k);
    else
      av = *(const f16x8*)(A2 + (size_t)am * K2 + (k - K1));
#pragma unroll
    for (int j = 0; j < 4; j++) {
      f16x8 bv = *(const f16x8*)(Bm + (size_t)(n0 + j * 16 + (lane & 15)) * Ktot + k);
      acc[j] = __builtin_amdgcn_mfma_f32_16x16x32_f16(av, bv, acc[j], 0, 0, 0);
    }
  }

  const int r0 = (lane >> 4) * 4;
  const int cc = lane & 15;
#pragma unroll
  for (int j = 0; j < 4; j++) {
    int col = n0 + j * 16 + cc;
    float bv = 0.f;
    if (bias1) bv += bias1[col];
    if (bias2) bv += bias2[col];
#pragma unroll
    for (int q = 0; q < 4; q++) {
      float v = acc[j][q] + bv;
      if (do_tanh) v = fast_tanh(v);
      C[(size_t)(m0 + r0 + q) * ldc + col] = (OutT)v;
    }
  }
}

// ---------------------------------------------------------------- attention scores/softmax/wc
// one block per (t,b): scores[s] = ctx[s,b,:].q ; softmax ; wc = a @ ctx[:,b,:]
__global__ __launch_bounds__(256) void attn_kernel(
    const float* __restrict__ Q,   // [4096][1024] f32
    const float* __restrict__ ctx, // context f32 [S=64][B=64][H=1024]
    f16* __restrict__ wc,          // [4096][1024] f16
    float* __restrict__ attn_out) {// [64][64] (t==63 only)
  const int m = blockIdx.x;
  const int b = m & 63;
  const int t = m >> 6;
  const int tid = threadIdx.x;
  const int lane = tid & 63;
  const int w = tid >> 6;
  __shared__ float s_sc[64];
  __shared__ float s_at[64];

  const float* qp = Q + (size_t)m * 1024 + lane * 16;
  float qf[16];
#pragma unroll
  for (int i = 0; i < 4; i++) {
    float4 v = *(const float4*)(qp + i * 4);
    qf[i * 4 + 0] = v.x; qf[i * 4 + 1] = v.y; qf[i * 4 + 2] = v.z; qf[i * 4 + 3] = v.w;
  }

  // scores: wave w handles s in [w*16, w*16+16)
  for (int si = 0; si < 16; si++) {
    int s = w * 16 + si;
    const float* cp = ctx + ((size_t)s * 64 + b) * 1024 + lane * 16;
    float d = 0.f;
#pragma unroll
    for (int i = 0; i < 4; i++) {
      float4 v = *(const float4*)(cp + i * 4);
      d += v.x * qf[i * 4] + v.y * qf[i * 4 + 1] + v.z * qf[i * 4 + 2] + v.w * qf[i * 4 + 3];
    }
#pragma unroll
    for (int off = 32; off > 0; off >>= 1) d += __shfl_down(d, off, 64);
    if (lane == 0) s_sc[s] = d;
  }
  __syncthreads();
  if (w == 0) {
    float v = s_sc[lane];
    float mx = v;
#pragma unroll
    for (int off = 32; off > 0; off >>= 1) mx = fmaxf(mx, __shfl_xor(mx, off, 64));
    float e = __expf(v - mx);
    float sm = e;
#pragma unroll
    for (int off = 32; off > 0; off >>= 1) sm += __shfl_xor(sm, off, 64);
    float a = e / sm;
    s_at[lane] = a;
    if (t == 63) attn_out[b * 64 + lane] = a;
  }
  __syncthreads();
#pragma unroll
  for (int rep = 0; rep < 4; rep++) {
    int h = rep * 256 + tid;
    float acc = 0.f;
    for (int s = 0; s < 64; s++)
      acc += s_at[s] * ctx[((size_t)s * 64 + b) * 1024 + h];
    wc[(size_t)m * 1024 + h] = (f16)acc;
  }
}

// ---------------------------------------------------------------- launch
extern "C" void kernel_launch(void* const* d_in, const int* in_sizes, int n_in,
                              void* d_out, int out_size, void* d_ws, size_t ws_size,
                              hipStream_t stream) {
  const int*   input = (const int*)d_in[0];
  const float* h0    = (const float*)d_in[1];
  const float* c0    = (const float*)d_in[2];
  const float* ctx   = (const float*)d_in[3];
  const float* emb   = (const float*)d_in[4];
  const float* w_ih  = (const float*)d_in[5];
  const float* w_hh  = (const float*)d_in[6];
  const float* b_ih  = (const float*)d_in[7];
  const float* b_hh  = (const float*)d_in[8];
  const float* w_in  = (const float*)d_in[9];
  const float* w_out = (const float*)d_in[10];
  float* out = (float*)d_out;

  char* ws = (char*)d_ws;
  size_t off = 0;
  auto alloc = [&](size_t bytes) {
    char* p = ws + off;
    off += (bytes + 255) & ~(size_t)255;
    return p;
  };
  f16*   h2hist = (f16*)alloc((size_t)65 * 65536 * 2);     // slot0=init, slot t+1=h2_t
  f16*   h1buf  = (f16*)alloc((size_t)2 * 65536 * 2);      // layer-1 h ping-pong
  float* Q      = (float*)alloc((size_t)4096 * 1024 * 4);  // f32 for attention accuracy
  f16*   wc     = (f16*)alloc((size_t)4096 * 1024 * 2);
  f16*   xg     = (f16*)alloc((size_t)4096 * 1024 * 2);    // gathered emb rows
  f16*   winh   = (f16*)alloc((size_t)1024 * 1024 * 2);
  f16*   wouth  = (f16*)alloc((size_t)1024 * 2048 * 2);
  unsigned* flags = (unsigned*)alloc(16384);               // 256 flags, 64B-padded

  float* outs = out;                              // [T*B][1024]
  float* hf   = out + (size_t)4096 * 1024;        // [2][64][1024]
  float* cf   = hf + 131072;
  float* attn = cf + 131072;                      // [64][64]

  // ---- small weight converts (only the ones still needed by K3/K5) + emb gather
  f2h_kernel<<<1024, 256, 0, stream>>>(w_in, winh);   // 1024*1024
  f2h_kernel<<<2048, 256, 0, stream>>>(w_out, wouth); // 1024*2048
  gather_rows<<<4096, 256, 0, stream>>>(emb, input, xg);
  init_h<<<256, 256, 0, stream>>>(h0, h1buf, h2hist, flags);

  // ---- K2: entire 64-step 2-layer LSTM in ONE cooperative kernel.
  // Weights in LDS; h exchange via agent-scope (sc1) batched asm loads (32-deep MLP)
  // + sc1 stores; store/poll flag barrier.
  {
    void* args[] = {(void*)&w_ih, (void*)&w_hh, (void*)&b_ih, (void*)&b_hh,
                    (void*)&c0, (void*)&xg, (void*)&h1buf, (void*)&h2hist,
                    (void*)&hf, (void*)&cf, (void*)&flags};
    hipLaunchCooperativeKernel(lstm_persistent, dim3(256), dim3(512), args, 0, stream);
  }

  // K3: Q = H2_all @ w_in^T   [M=4096,N=1024,K=1024], f32 out
  gemm_simple<float><<<dim3(16, 64), 256, 0, stream>>>(h2hist + 65536, nullptr,
      winh, nullptr, nullptr, Q, 1024, 1024, 1024, 0);

  // K4: scores -> softmax -> weighted context (+ final-step attention output), all f32
  attn_kernel<<<4096, 256, 0, stream>>>(Q, ctx, wc, attn);

  // K5: outs = tanh([wc | H2_all] @ w_out^T)   [M=4096,N=1024,K=2048], f32 out
  gemm_simple<float><<<dim3(16, 64), 256, 0, stream>>>(wc, h2hist + 65536,
      wouth, nullptr, nullptr, outs, 1024, 1024, 2048, 1);
}

// Round 6
// 1540.534 us; speedup vs baseline: 2.4064x; 1.0402x over previous
//
#include <hip/hip_runtime.h>

typedef _Float16 f16;
typedef __attribute__((ext_vector_type(4))) _Float16 f16x4;
typedef __attribute__((ext_vector_type(8))) _Float16 f16x8;
typedef __attribute__((ext_vector_type(4))) float f32x4;

// ---------------------------------------------------------------- helpers
__device__ __forceinline__ float fast_sig(float x) { return 1.f / (1.f + __expf(-x)); }
// tanh via 1 - 2/(e^{2x}+1): saturates cleanly to +/-1, no NaN at extremes
__device__ __forceinline__ float fast_tanh(float x) {
  float e = __expf(2.f * x);
  return 1.f - 2.f / (e + 1.f);
}

// ---------------------------------------------------------------- f32 -> f16 convert
__global__ __launch_bounds__(256) void f2h_kernel(const float* __restrict__ src,
                                                  f16* __restrict__ dst) {
  size_t i = ((size_t)blockIdx.x * 256 + threadIdx.x) * 4;
  float4 v = *(const float4*)(src + i);
  dst[i + 0] = (f16)v.x;
  dst[i + 1] = (f16)v.y;
  dst[i + 2] = (f16)v.z;
  dst[i + 3] = (f16)v.w;
}

// gather embedding rows: xg[m,:] = (f16)emb[ids[m],:]   (one block per m, H=1024)
__global__ __launch_bounds__(256) void gather_rows(const float* __restrict__ emb,
                                                   const int* __restrict__ ids,
                                                   f16* __restrict__ xg) {
  int m = blockIdx.x;
  int i = threadIdx.x * 4;
  const float* src = emb + (size_t)ids[m] * 1024 + i;
  float4 v = *(const float4*)src;
  f16* d = xg + (size_t)m * 1024 + i;
  d[0] = (f16)v.x; d[1] = (f16)v.y; d[2] = (f16)v.z; d[3] = (f16)v.w;
}

// ---------------------------------------------------------------- h-state init + flag reset
__global__ __launch_bounds__(256) void init_h(const float* __restrict__ h0,
                                              f16* __restrict__ h1slot0,
                                              f16* __restrict__ h2slot0,
                                              unsigned* __restrict__ flags) {
  int i = blockIdx.x * 256 + threadIdx.x;  // grid 256 -> 65536
  h1slot0[i] = (f16)h0[i];
  h2slot0[i] = (f16)h0[65536 + i];
  if (i < 4096) flags[i] = 0;              // 256 flags, 64B-padded (stride 16 u32)
}

// ---------------------------------------------------------------- persistent 2-layer LSTM
// One cooperative launch runs all 64 timesteps. 256 blocks x 512 threads (8 waves),
// block p owns hidden units [4p,4p+4) of BOTH layers: 16 gate-rows x 4 matrices
// (Wih1,Whh1,Wih2,Whh2) = 128 KB f16 staged into LDS ONCE.
// Phase t computes layer1_t and layer2_{t-1} in one merged pass.
// Cost evolution (measured, per phase): cg::grid.sync ~46us; LLC atomic counter
// ~22us; store/poll flags ~21.8us; batched 32-deep sc1 load burst ~15.4us.
// Diagnosis: sc1 LOADS bypass the per-XCD L2 -> all 32 blocks/XCD re-fetch the
// same 256 KB of h from the LLC = 64 MB/phase. Fix WITHOUT fences:
// WRITE-ONCE ADDRESSES. h1 becomes a 65-slot history (like h2hist), so every h
// slot's address is written exactly once (sc1, write-through to LLC, ordered
// before the flag by the pre-barrier vmcnt drain) and never resides in any L2
// before its producing phase. Normal cached reads are then trivially coherent:
// first block per XCD misses to the LLC (fresh by construction), the other 31
// blocks hit their XCD's L2. No buffer_inv, no stale-line hazard, no dirty-line
// hazard. (Round-5's fence variant is abandoned: buffer_inv can drop dirty
// output lines and a coherence failure in a spin-barrier kernel hangs the GPU.)
__global__ __launch_bounds__(512, 1) void lstm_persistent(
    const float* __restrict__ w_ih, const float* __restrict__ w_hh,  // [2][4096][1024] f32
    const float* __restrict__ b_ih, const float* __restrict__ b_hh,  // [2][4096] f32
    const float* __restrict__ c0,                                    // [2][64][1024] f32
    const f16* __restrict__ xg,                                      // [4096][1024] f16
    f16* __restrict__ h1hist,                                        // 65 slots (slot0 = init)
    f16* __restrict__ h2hist,                                        // 65 slots (slot0 = init)
    float* __restrict__ hf, float* __restrict__ cf,                  // [2][64][1024] f32
    unsigned* __restrict__ flags) {                                  // [256] stride-16 u32
  __shared__ f16 wlds[65536];               // 4 matrices x 2048 slots x 8 f16 = 128 KB
  __shared__ float red1[2048], red2[2048];  // [wave][16m][16n] partials, 8 KB each
  __shared__ float bsum[32];                // b_ih+b_hh for this block's 16 rows x 2 layers
  const int p = blockIdx.x;
  const int tid = threadIdx.x;
  const int lane = tid & 63, w = tid >> 6;
  const int mt = w & 3, kh = w >> 2;        // wave = (batch-tile, K-half)
  const int am = mt * 16 + (lane & 15);     // A-fragment batch row
  const int kq = (lane >> 4) * 8;

  // ---- one-time staging: 8192 slots / 512 threads = 16 each
  for (int s = tid; s < 8192; s += 512) {
    const int mat = s >> 11, sl = s & 2047;       // mat: 0=Wih1 1=Whh1 2=Wih2 3=Whh2
    const int ln = sl & 63, ks = sl >> 6;
    const int n = ln & 15;                        // n = gate*4 + unit_local
    const int row = (n >> 2) * 1024 + p * 4 + (n & 3) + ((mat >= 2) ? 4096 : 0);
    const int k = ks * 32 + (ln >> 4) * 8;
    const float* src = ((mat & 1) ? w_hh : w_ih) + (size_t)row * 1024 + k;
    float4 v0 = *(const float4*)src;
    float4 v1 = *(const float4*)(src + 4);
    f16x8 hv = {(f16)v0.x, (f16)v0.y, (f16)v0.z, (f16)v0.w,
                (f16)v1.x, (f16)v1.y, (f16)v1.z, (f16)v1.w};
    *(f16x8*)(wlds + (size_t)mat * 16384 + (size_t)sl * 8) = hv;
  }
  if (tid < 32) {
    int l = tid >> 4, n = tid & 15;
    int row = l * 4096 + (n >> 2) * 1024 + p * 4 + (n & 3);
    bsum[tid] = b_ih[row] + b_hh[row];
  }
  float creg;
  {
    int q = tid & 255;
    size_t idx = (size_t)(q >> 2) * 1024 + p * 4 + (q & 3);
    creg = (tid < 256) ? c0[idx] : c0[65536 + idx];
  }
  __syncthreads();

  for (int t = 0; t <= 64; ++t) {
    // clamped addresses so edge phases stay straight-line (MFMA predicated off)
    const int tx = (t < 64) ? t : 63;
    const int t2 = (t > 0) ? t - 1 : 0;
    // per-lane k-base for this wave: k = ks*32 + kq, ks in [kh*16, kh*16+16)
    const f16* xrow  = xg + ((size_t)tx * 64 + am) * 1024 + kh * 512 + kq;
    const f16* hrow  = h1hist + ((size_t)t * 64 + am) * 1024 + kh * 512 + kq;   // h1_{t-1}
    const f16* h2row = h2hist + ((size_t)t2 * 64 + am) * 1024 + kh * 512 + kq;  // h2_{t-2}

    f32x4 acc1 = {0.f, 0.f, 0.f, 0.f};
    f32x4 acc2 = {0.f, 0.f, 0.f, 0.f};
    // h reads: NORMAL cached loads. Slot addresses are write-once, so no L2 can
    // hold a stale copy; L2 broadcasts within each XCD (32x traffic reduction
    // vs sc1 reads).
#pragma unroll
    for (int i = 0; i < 16; ++i) {
      const int ks = kh * 16 + i;
      f16x8 xv  = *(const f16x8*)(xrow + i * 32);
      f16x8 hv  = *(const f16x8*)(hrow + i * 32);
      f16x8 h2v = *(const f16x8*)(h2row + i * 32);
      f16x8 b0 = *(const f16x8*)(wlds + (size_t)ks * 512 + lane * 8);
      f16x8 b1 = *(const f16x8*)(wlds + 16384 + (size_t)ks * 512 + lane * 8);
      f16x8 b2 = *(const f16x8*)(wlds + 32768 + (size_t)ks * 512 + lane * 8);
      f16x8 b3 = *(const f16x8*)(wlds + 49152 + (size_t)ks * 512 + lane * 8);
      if (t < 64) {  // layer-1 gates, timestep t
        acc1 = __builtin_amdgcn_mfma_f32_16x16x32_f16(xv, b0, acc1, 0, 0, 0);
        acc1 = __builtin_amdgcn_mfma_f32_16x16x32_f16(hv, b1, acc1, 0, 0, 0);
      }
      if (t > 0) {   // layer-2 gates, timestep t-1
        acc2 = __builtin_amdgcn_mfma_f32_16x16x32_f16(hv, b2, acc2, 0, 0, 0);
        acc2 = __builtin_amdgcn_mfma_f32_16x16x32_f16(h2v, b3, acc2, 0, 0, 0);
      }
    }

    if (t < 64) {
#pragma unroll
      for (int q = 0; q < 4; q++)
        red1[w * 256 + ((lane >> 4) * 4 + q) * 16 + (lane & 15)] = acc1[q];
    }
    if (t > 0) {
#pragma unroll
      for (int q = 0; q < 4; q++)
        red2[w * 256 + ((lane >> 4) * 4 + q) * 16 + (lane & 15)] = acc2[q];
    }
    __syncthreads();

    // ---- elementwise: threads 0-255 -> layer1, 256-511 -> layer2
    if (t < 64 && tid < 256) {
      const int b = tid >> 2, ul = tid & 3;
      const int mrow = (b & 15) * 16, mtb = (b >> 4) * 256;
      float g4[4];
#pragma unroll
      for (int g = 0; g < 4; g++) {
        int n = g * 4 + ul;
        g4[g] = red1[mtb + mrow + n] + red1[1024 + mtb + mrow + n] + bsum[n];
      }
      float cn = fast_sig(g4[1]) * creg + fast_sig(g4[0]) * fast_tanh(g4[2]);
      float hn = fast_sig(g4[3]) * fast_tanh(cn);
      creg = cn;
      const int u = p * 4 + ul;
      if (t == 63) {
        hf[(size_t)b * 1024 + u] = hn;
        cf[(size_t)b * 1024 + u] = cn;
      }
      // pack 4 units (ul=0..3, same wave) -> one 8B agent-scope store
      float h1v = __shfl_down(hn, 1, 64);
      float h2s = __shfl_down(hn, 2, 64);
      float h3v = __shfl_down(hn, 3, 64);
      if (ul == 0) {
        union { f16x4 h; unsigned long long u64; } pk;
        pk.h = (f16x4){(f16)hn, (f16)h1v, (f16)h2s, (f16)h3v};
        f16* dst = h1hist + (size_t)(t + 1) * 65536 + (size_t)b * 1024 + p * 4;
        __hip_atomic_store((unsigned long long*)dst, pk.u64,
                           __ATOMIC_RELAXED, __HIP_MEMORY_SCOPE_AGENT);
      }
    }
    if (t > 0 && tid >= 256) {
      const int q = tid & 255;
      const int b = q >> 2, ul = q & 3;
      const int mrow = (b & 15) * 16, mtb = (b >> 4) * 256;
      float g4[4];
#pragma unroll
      for (int g = 0; g < 4; g++) {
        int n = g * 4 + ul;
        g4[g] = red2[mtb + mrow + n] + red2[1024 + mtb + mrow + n] + bsum[16 + n];
      }
      float cn = fast_sig(g4[1]) * creg + fast_sig(g4[0]) * fast_tanh(g4[2]);
      float hn = fast_sig(g4[3]) * fast_tanh(cn);
      creg = cn;
      const int u = p * 4 + ul;
      if (t == 64) {
        hf[65536 + (size_t)b * 1024 + u] = hn;
        cf[65536 + (size_t)b * 1024 + u] = cn;
      }
      float h1v = __shfl_down(hn, 1, 64);
      float h2s = __shfl_down(hn, 2, 64);
      float h3v = __shfl_down(hn, 3, 64);
      if (ul == 0) {
        union { f16x4 h; unsigned long long u64; } pk;
        pk.h = (f16x4){(f16)hn, (f16)h1v, (f16)h2s, (f16)h3v};
        f16* dst = h2hist + (size_t)t * 65536 + (size_t)b * 1024 + p * 4;
        __hip_atomic_store((unsigned long long*)dst, pk.u64,
                           __ATOMIC_RELAXED, __HIP_MEMORY_SCOPE_AGENT);
      }
    }

    if (t < 64) {
      // store/poll flag barrier (no RMW):
      // __syncthreads drains every wave's vmcnt -> all agent stores at LLC.
      __syncthreads();
      const unsigned epoch = (unsigned)(t + 1);
      if (w == 0) {
        if (lane == 0)
          __hip_atomic_store(flags + (size_t)p * 16, epoch,
                             __ATOMIC_RELAXED, __HIP_MEMORY_SCOPE_AGENT);
        for (;;) {  // each lane watches 4 blocks' flags (64B-padded lines)
          bool ok = true;
#pragma unroll
          for (int j = 0; j < 4; j++) {
            unsigned v = __hip_atomic_load(flags + (size_t)(lane * 4 + j) * 16,
                                           __ATOMIC_RELAXED, __HIP_MEMORY_SCOPE_AGENT);
            ok &= (v >= epoch);
          }
          if (__all(ok)) break;
          __builtin_amdgcn_s_sleep(1);
        }
      }
      __syncthreads();
    }
  }
}

// ---------------------------------------------------------------- simple direct-global GEMM
// C[m,n] = sum_k A[m,k]*B[n,k] (+bias1+bias2)(tanh). A = A1 rows [*,K1] then A2 for k>=K1.
// B row-major [N, Ktot], all f16. Block = 64x64 tile, 4 waves; wave w owns 16 m-rows.
template <typename OutT>
__global__ __launch_bounds__(256) void gemm_simple(
    const f16* __restrict__ A1, const f16* __restrict__ A2,
    const f16* __restrict__ Bm,
    const float* __restrict__ bias1, const float* __restrict__ bias2,
    OutT* __restrict__ C, int ldc,
    int K1, int Ktot, int do_tanh) {
  const int tid = threadIdx.x;
  const int lane = tid & 63;
  const int w = tid >> 6;
  const int m0 = blockIdx.y * 64 + w * 16;  // this wave's 16 m-rows
  const int n0 = blockIdx.x * 64;
  const int am = m0 + (lane & 15);
  const int kq = (lane >> 4) * 8;           // quad's k-offset within a 32-chunk
  const int K2 = Ktot - K1;

  f32x4 acc[4];
#pragma unroll
  for (int j = 0; j < 4; j++) acc[j] = (f32x4){0.f, 0.f, 0.f, 0.f};

  for (int k0 = 0; k0 < Ktot; k0 += 32) {
    int k = k0 + kq;
    f16x8 av;
    if (k < K1)
      av = *(const f16x8*)(A1 + (size_t)am * K1 + k);
    else
      av = *(const f16x8*)(A2 + (size_t)am * K2 + (k - K1));
#pragma unroll
    for (int j = 0; j < 4; j++) {
      f16x8 bv = *(const f16x8*)(Bm + (size_t)(n0 + j * 16 + (lane & 15)) * Ktot + k);
      acc[j] = __builtin_amdgcn_mfma_f32_16x16x32_f16(av, bv, acc[j], 0, 0, 0);
    }
  }

  const int r0 = (lane >> 4) * 4;
  const int cc = lane & 15;
#pragma unroll
  for (int j = 0; j < 4; j++) {
    int col = n0 + j * 16 + cc;
    float bv = 0.f;
    if (bias1) bv += bias1[col];
    if (bias2) bv += bias2[col];
#pragma unroll
    for (int q = 0; q < 4; q++) {
      float v = acc[j][q] + bv;
      if (do_tanh) v = fast_tanh(v);
      C[(size_t)(m0 + r0 + q) * ldc + col] = (OutT)v;
    }
  }
}

// ---------------------------------------------------------------- attention scores/softmax/wc
// one block per (t,b): scores[s] = ctx[s,b,:].q ; softmax ; wc = a @ ctx[:,b,:]
__global__ __launch_bounds__(256) void attn_kernel(
    const float* __restrict__ Q,   // [4096][1024] f32
    const float* __restrict__ ctx, // context f32 [S=64][B=64][H=1024]
    f16* __restrict__ wc,          // [4096][1024] f16
    float* __restrict__ attn_out) {// [64][64] (t==63 only)
  const int m = blockIdx.x;
  const int b = m & 63;
  const int t = m >> 6;
  const int tid = threadIdx.x;
  const int lane = tid & 63;
  const int w = tid >> 6;
  __shared__ float s_sc[64];
  __shared__ float s_at[64];

  const float* qp = Q + (size_t)m * 1024 + lane * 16;
  float qf[16];
#pragma unroll
  for (int i = 0; i < 4; i++) {
    float4 v = *(const float4*)(qp + i * 4);
    qf[i * 4 + 0] = v.x; qf[i * 4 + 1] = v.y; qf[i * 4 + 2] = v.z; qf[i * 4 + 3] = v.w;
  }

  // scores: wave w handles s in [w*16, w*16+16)
  for (int si = 0; si < 16; si++) {
    int s = w * 16 + si;
    const float* cp = ctx + ((size_t)s * 64 + b) * 1024 + lane * 16;
    float d = 0.f;
#pragma unroll
    for (int i = 0; i < 4; i++) {
      float4 v = *(const float4*)(cp + i * 4);
      d += v.x * qf[i * 4] + v.y * qf[i * 4 + 1] + v.z * qf[i * 4 + 2] + v.w * qf[i * 4 + 3];
    }
#pragma unroll
    for (int off = 32; off > 0; off >>= 1) d += __shfl_down(d, off, 64);
    if (lane == 0) s_sc[s] = d;
  }
  __syncthreads();
  if (w == 0) {
    float v = s_sc[lane];
    float mx = v;
#pragma unroll
    for (int off = 32; off > 0; off >>= 1) mx = fmaxf(mx, __shfl_xor(mx, off, 64));
    float e = __expf(v - mx);
    float sm = e;
#pragma unroll
    for (int off = 32; off > 0; off >>= 1) sm += __shfl_xor(sm, off, 64);
    float a = e / sm;
    s_at[lane] = a;
    if (t == 63) attn_out[b * 64 + lane] = a;
  }
  __syncthreads();
#pragma unroll
  for (int rep = 0; rep < 4; rep++) {
    int h = rep * 256 + tid;
    float acc = 0.f;
    for (int s = 0; s < 64; s++)
      acc += s_at[s] * ctx[((size_t)s * 64 + b) * 1024 + h];
    wc[(size_t)m * 1024 + h] = (f16)acc;
  }
}

// ---------------------------------------------------------------- launch
extern "C" void kernel_launch(void* const* d_in, const int* in_sizes, int n_in,
                              void* d_out, int out_size, void* d_ws, size_t ws_size,
                              hipStream_t stream) {
  const int*   input = (const int*)d_in[0];
  const float* h0    = (const float*)d_in[1];
  const float* c0    = (const float*)d_in[2];
  const float* ctx   = (const float*)d_in[3];
  const float* emb   = (const float*)d_in[4];
  const float* w_ih  = (const float*)d_in[5];
  const float* w_hh  = (const float*)d_in[6];
  const float* b_ih  = (const float*)d_in[7];
  const float* b_hh  = (const float*)d_in[8];
  const float* w_in  = (const float*)d_in[9];
  const float* w_out = (const float*)d_in[10];
  float* out = (float*)d_out;

  char* ws = (char*)d_ws;
  size_t off = 0;
  auto alloc = [&](size_t bytes) {
    char* p = ws + off;
    off += (bytes + 255) & ~(size_t)255;
    return p;
  };
  f16*   h2hist = (f16*)alloc((size_t)65 * 65536 * 2);     // slot0=init, slot t+1=h2_t
  f16*   h1hist = (f16*)alloc((size_t)65 * 65536 * 2);     // slot0=init, slot t+1=h1_t
  float* Q      = (float*)alloc((size_t)4096 * 1024 * 4);  // f32 for attention accuracy
  f16*   wc     = (f16*)alloc((size_t)4096 * 1024 * 2);
  f16*   xg     = (f16*)alloc((size_t)4096 * 1024 * 2);    // gathered emb rows
  f16*   winh   = (f16*)alloc((size_t)1024 * 1024 * 2);
  f16*   wouth  = (f16*)alloc((size_t)1024 * 2048 * 2);
  unsigned* flags = (unsigned*)alloc(16384);               // 256 flags, 64B-padded

  float* outs = out;                              // [T*B][1024]
  float* hf   = out + (size_t)4096 * 1024;        // [2][64][1024]
  float* cf   = hf + 131072;
  float* attn = cf + 131072;                      // [64][64]

  // ---- small weight converts (only the ones still needed by K3/K5) + emb gather
  f2h_kernel<<<1024, 256, 0, stream>>>(w_in, winh);   // 1024*1024
  f2h_kernel<<<2048, 256, 0, stream>>>(w_out, wouth); // 1024*2048
  gather_rows<<<4096, 256, 0, stream>>>(emb, input, xg);
  init_h<<<256, 256, 0, stream>>>(h0, h1hist, h2hist, flags);

  // ---- K2: entire 64-step 2-layer LSTM in ONE cooperative kernel.
  // Weights in LDS; h writes agent-scope sc1 into WRITE-ONCE history slots;
  // h reads normal cached loads (L2-shared per XCD); store/poll flag barrier.
  {
    void* args[] = {(void*)&w_ih, (void*)&w_hh, (void*)&b_ih, (void*)&b_hh,
                    (void*)&c0, (void*)&xg, (void*)&h1hist, (void*)&h2hist,
                    (void*)&hf, (void*)&cf, (void*)&flags};
    hipLaunchCooperativeKernel(lstm_persistent, dim3(256), dim3(512), args, 0, stream);
  }

  // K3: Q = H2_all @ w_in^T   [M=4096,N=1024,K=1024], f32 out
  gemm_simple<float><<<dim3(16, 64), 256, 0, stream>>>(h2hist + 65536, nullptr,
      winh, nullptr, nullptr, Q, 1024, 1024, 1024, 0);

  // K4: scores -> softmax -> weighted context (+ final-step attention output), all f32
  attn_kernel<<<4096, 256, 0, stream>>>(Q, ctx, wc, attn);

  // K5: outs = tanh([wc | H2_all] @ w_out^T)   [M=4096,N=1024,K=2048], f32 out
  gemm_simple<float><<<dim3(16, 64), 256, 0, stream>>>(wc, h2hist + 65536,
      wouth, nullptr, nullptr, outs, 1024, 1024, 2048, 1);
}